// Round 1
// baseline (1327.008 us; speedup 1.0000x reference)
//
#include <hip/hip_runtime.h>
#include <hip/hip_bf16.h>

#define HD 256
#define CD 512
#define VD 32000
#define ND 64
#define TD 512

typedef __attribute__((ext_vector_type(8))) short short8;
typedef __attribute__((ext_vector_type(4))) float floatx4;

__device__ inline float bf2f(unsigned short u) {
  union { unsigned u; float f; } t; t.u = ((unsigned)u) << 16; return t.f;
}
__device__ inline unsigned short f2bf(float x) {
  union { float f; unsigned u; } t; t.f = x;
  unsigned u = t.u;
  u += 0x7FFFu + ((u >> 16) & 1u);
  return (unsigned short)(u >> 16);
}
__device__ inline float bf_lo(unsigned u) { union { unsigned u; float f; } t; t.u = u << 16; return t.f; }
__device__ inline float bf_hi(unsigned u) { union { unsigned u; float f; } t; t.u = u & 0xFFFF0000u; return t.f; }

__device__ inline floatx4 zf4() { floatx4 v; v[0] = v[1] = v[2] = v[3] = 0.f; return v; }
__device__ inline floatx4 mfma16(short8 a, short8 b, floatx4 c) {
  return __builtin_amdgcn_mfma_f32_16x16x32_bf16(a, b, c, 0, 0, 0);
}

// ---------------- small start-vector kernels ----------------

__global__ void k_fx(const float* __restrict__ emb, const float* __restrict__ W,
                     const float* __restrict__ b, float* __restrict__ out) {
  __shared__ float e[HD];
  int j = threadIdx.x;
  e[j] = emb[j];
  __syncthreads();
  float a = b[j];
#pragma unroll 4
  for (int i = 0; i < HD; ++i) a += e[i] * W[i * HD + j];
  out[j] = a;
}

// x (rows x 256) -> two ResLayers -> out  (one block per row, 256 threads)
__global__ void k_mlp(const float* __restrict__ inp, const float* __restrict__ rw,
                      const float* __restrict__ rb, float* __restrict__ out) {
  __shared__ float x[HD], h[HD];
  int j = threadIdx.x;
  int row = blockIdx.x;
  x[j] = inp[row * HD + j];
  __syncthreads();
  for (int L = 0; L < 2; ++L) {
    const float* w1 = rw + (size_t)(L * 2 + 0) * HD * HD;
    const float* b1 = rb + (L * 2 + 0) * HD;
    const float* w2 = rw + (size_t)(L * 2 + 1) * HD * HD;
    const float* b2 = rb + (L * 2 + 1) * HD;
    float a = b1[j];
#pragma unroll 4
    for (int i = 0; i < HD; ++i) a += x[i] * w1[i * HD + j];
    a = fmaxf(a, 0.f);
    h[j] = a;
    __syncthreads();
    float o = b2[j];
#pragma unroll 4
    for (int i = 0; i < HD; ++i) o += h[i] * w2[i * HD + j];
    x[j] = x[j] + fmaxf(o, 0.f);
    __syncthreads();
  }
  out[row * HD + j] = x[j];
}

// start logits + log_softmax (1 block, 256 threads)
__global__ void k_slog(const float* __restrict__ fx, const float* __restrict__ nextE,
                       float* __restrict__ startO) {
  __shared__ float x[HD];
  __shared__ float red[4];
  int j = threadIdx.x;
  x[j] = fx[j];
  __syncthreads();
  float lg0 = 0.f, lg1 = 0.f;
#pragma unroll 4
  for (int hh = 0; hh < HD; ++hh) {
    float xv = x[hh];
    lg0 += xv * nextE[j * HD + hh];
    lg1 += xv * nextE[(j + 256) * HD + hh];
  }
  float m = fmaxf(lg0, lg1);
#pragma unroll
  for (int sh = 1; sh <= 32; sh <<= 1) m = fmaxf(m, __shfl_xor(m, sh));
  if ((j & 63) == 0) red[j >> 6] = m;
  __syncthreads();
  m = fmaxf(fmaxf(red[0], red[1]), fmaxf(red[2], red[3]));
  __syncthreads();
  float s = __expf(lg0 - m) + __expf(lg1 - m);
#pragma unroll
  for (int sh = 1; sh <= 32; sh <<= 1) s += __shfl_xor(s, sh);
  if ((j & 63) == 0) red[j >> 6] = s;
  __syncthreads();
  s = red[0] + red[1] + red[2] + red[3];
  float ls = __logf(s);
  startO[j] = lg0 - m - ls;
  startO[j + 256] = lg1 - m - ls;
}

// ---------------- generic NT GEMM (M x 256) x (N x 256)^T -> bf16 out[M][N] ----------------
// tiles 128x128, K=256, 512 threads, out col count = 512 always here.
#define GEMM_LDS (2 * 128 * 528)
__global__ __launch_bounds__(512) void k_gemm(const float* __restrict__ A,
                                              const float* __restrict__ B,
                                              unsigned short* __restrict__ out,
                                              int ldo) {
  extern __shared__ char smem[];
  char* sA = smem;             // [128][528 bytes] bf16, K contiguous
  char* sB = smem + 128 * 528;
  const int tid = threadIdx.x;
  const int mbase = blockIdx.x * 128, nbase = blockIdx.y * 128;
  {
    int row = tid >> 2, seg = tid & 3;
    const float4* srcA = (const float4*)(A + (size_t)(mbase + row) * HD + seg * 64);
    const float4* srcB = (const float4*)(B + (size_t)(nbase + row) * HD + seg * 64);
    uint2* dA = (uint2*)(sA + row * 528 + seg * 128);
    uint2* dB = (uint2*)(sB + row * 528 + seg * 128);
#pragma unroll
    for (int i = 0; i < 16; ++i) {
      float4 va = srcA[i];
      float4 vb = srcB[i];
      dA[i] = make_uint2((unsigned)f2bf(va.x) | ((unsigned)f2bf(va.y) << 16),
                         (unsigned)f2bf(va.z) | ((unsigned)f2bf(va.w) << 16));
      dB[i] = make_uint2((unsigned)f2bf(vb.x) | ((unsigned)f2bf(vb.y) << 16),
                         (unsigned)f2bf(vb.z) | ((unsigned)f2bf(vb.w) << 16));
    }
  }
  __syncthreads();
  const int w = tid >> 6, l = tid & 63, l15 = l & 15, quad = l >> 4;
  floatx4 acc[8];
#pragma unroll
  for (int nt = 0; nt < 8; ++nt) acc[nt] = zf4();
  const char* arow = sA + (w * 16 + l15) * 528 + quad * 16;
  const char* brow = sB + l15 * 528 + quad * 16;
#pragma unroll
  for (int kc = 0; kc < 8; ++kc) {
    short8 a = *(const short8*)(arow + kc * 64);
#pragma unroll
    for (int nt = 0; nt < 8; ++nt) {
      short8 b = *(const short8*)(brow + nt * 16 * 528 + kc * 64);
      acc[nt] = mfma16(a, b, acc[nt]);
    }
  }
#pragma unroll
  for (int nt = 0; nt < 8; ++nt)
#pragma unroll
    for (int r = 0; r < 4; ++r) {
      int m = mbase + w * 16 + quad * 4 + r;
      int n = nbase + nt * 16 + l15;
      out[(size_t)m * ldo + n] = f2bf(acc[nt][r]);
    }
}

// ---------------- transition row-softmax: bf16 logits [512][512] -> P bf16 ----------------
__global__ void k_smrow(const unsigned short* __restrict__ lg, unsigned short* __restrict__ P) {
  __shared__ float red[4];
  int row = blockIdx.x, j = threadIdx.x;
  float v0 = bf2f(lg[row * CD + j]);
  float v1 = bf2f(lg[row * CD + 256 + j]);
  float m = fmaxf(v0, v1);
#pragma unroll
  for (int sh = 1; sh <= 32; sh <<= 1) m = fmaxf(m, __shfl_xor(m, sh));
  if ((j & 63) == 0) red[j >> 6] = m;
  __syncthreads();
  m = fmaxf(fmaxf(red[0], red[1]), fmaxf(red[2], red[3]));
  __syncthreads();
  float e0 = __expf(v0 - m), e1 = __expf(v1 - m);
  float s = e0 + e1;
#pragma unroll
  for (int sh = 1; sh <= 32; sh <<= 1) s += __shfl_xor(s, sh);
  if ((j & 63) == 0) red[j >> 6] = s;
  __syncthreads();
  s = red[0] + red[1] + red[2] + red[3];
  float inv = 1.f / s;
  P[row * CD + j] = f2bf(e0 * inv);
  P[row * CD + 256 + j] = f2bf(e1 * inv);
}

// transpose P (bf16 512x512) -> PT
__global__ __launch_bounds__(512) void k_tr(const unsigned short* __restrict__ P,
                                            unsigned short* __restrict__ PT) {
  __shared__ unsigned short t[128][136];
  int rb = blockIdx.x * 128, cb = blockIdx.y * 128;
  int tid = threadIdx.x;
  int r = tid >> 2, c0 = (tid & 3) * 32;
  for (int i = 0; i < 32; ++i) t[r][c0 + i] = P[(rb + r) * CD + cb + c0 + i];
  __syncthreads();
  int c = tid >> 2, r0 = (tid & 3) * 32;
  for (int i = 0; i < 32; ++i) PT[(cb + c) * CD + rb + r0 + i] = t[r0 + i][c];
}

// ---------------- vocab log-sum-exp over columns of logT [V][C] ----------------
__global__ __launch_bounds__(512) void k_lsep(const unsigned short* __restrict__ logT,
                                              float* __restrict__ part) {
  int c = threadIdx.x, b = blockIdx.x;
  const unsigned short* p = logT + (size_t)b * 256 * CD + c;
  float m = -1e30f, s = 0.f;
  for (int i = 0; i < 256; ++i) {
    float v = bf2f(p[(size_t)i * CD]);
    float nm = fmaxf(m, v);
    s = s * __expf(m - nm) + __expf(v - nm);
    m = nm;
  }
  part[b * 1024 + c] = m;
  part[b * 1024 + 512 + c] = s;
}

__global__ void k_lsef(const float* __restrict__ part, float* __restrict__ lse) {
  int c = threadIdx.x;
  float m = -1e30f, s = 0.f;
  for (int i = 0; i < 125; ++i) {
    float mi = part[i * 1024 + c], si = part[i * 1024 + 512 + c];
    float nm = fmaxf(m, mi);
    s = s * __expf(m - nm) + si * __expf(mi - nm);
    m = nm;
  }
  lse[c] = m + __logf(s);
}

// ---------------- gather emission log-probs into MFMA C/D-layout order ----------------
// em layout: element offset = ((b*8 + w)*64 + l)*16 + j,  b = g*256 + t_local
// j = nt*4 + r ;  c = w*64 + nt*16 + (l&15) ; n = (g&3)*16 + (l>>4)*4 + r
__global__ __launch_bounds__(512) void k_gather(const int* __restrict__ text,
                                                const unsigned short* __restrict__ logT,
                                                const float* __restrict__ lse,
                                                unsigned short* __restrict__ em) {
  const int b = blockIdx.x;
  const int g = b >> 8, t = b & 255;
  const int dir = g >> 2, q = g & 3;
  const int tg = dir ? (511 - t) : t;
  const int tid = threadIdx.x, w = tid >> 6, l = tid & 63;
  const int l15 = l & 15, quad = l >> 4;
  unsigned outp[8];
#pragma unroll
  for (int j2 = 0; j2 < 8; ++j2) {
    int j0 = 2 * j2;
    int nt = j0 >> 2;
    int c = w * 64 + nt * 16 + l15;
    float base = lse[c];
    int r0 = j0 & 3;
    int n0 = q * 16 + quad * 4 + r0;
    int tok0 = text[n0 * TD + tg];
    int tok1 = text[(n0 + 1) * TD + tg];
    float v0 = bf2f(logT[(size_t)tok0 * CD + c]) - base;
    float v1 = bf2f(logT[(size_t)tok1 * CD + c]) - base;
    outp[j2] = (unsigned)f2bf(v0) | ((unsigned)f2bf(v1) << 16);
  }
  uint4* dst = (uint4*)(em + ((size_t)(b * 8 + w) * 64 + l) * 16);
  dst[0] = make_uint4(outp[0], outp[1], outp[2], outp[3]);
  dst[1] = make_uint4(outp[4], outp[5], outp[6], outp[7]);
}

// ---------------- the scan: 8 blocks (4 fwd + 4 bwd), 16 seqs each, P resident ----------------
#define SCAN_LDS (16 * 1040 + 8 * 16384 + 512)
__global__ __launch_bounds__(512, 2) void k_scan(const unsigned short* __restrict__ Pmat,
                                                 const unsigned short* __restrict__ PTmat,
                                                 const unsigned short* __restrict__ em,
                                                 const float* __restrict__ startv,
                                                 float* __restrict__ alphaF,
                                                 float* __restrict__ alphaB) {
  extern __shared__ char smem[];
  char* Abuf = smem;                              // bf16 A[row 0..15][col 0..511], row stride 1040 B
  char* Plds = smem + 16 * 1040;                  // 8 wave regions x 16 KB (k rows 384..511)
  float* scratch = (float*)(smem + 16 * 1040 + 131072);  // [16 rows][8 waves]

  const int g = blockIdx.x, dir = g >> 2, q = g & 3;
  const int tid = threadIdx.x, w = tid >> 6, l = tid & 63;
  const int l15 = l & 15, quad = l >> 4;
  const int colbase = w * 64;
  const unsigned short* Pb = dir ? Pmat : PTmat;  // B-frag source: element [col*512 + k]

  // P k-rows 0..383 resident in registers (MFMA B fragments)
  short8 Prf[12][4];
#pragma unroll
  for (int kc = 0; kc < 12; ++kc)
#pragma unroll
    for (int nt = 0; nt < 4; ++nt)
      Prf[kc][nt] = *(const short8*)(Pb + (size_t)(colbase + nt * 16 + l15) * CD + kc * 32 + quad * 8);

  // P k-rows 384..511 into this wave's LDS region, XOR-swizzled 16B units
  char* preg = Plds + w * 16384;
  for (int i = 0; i < 16; ++i) {
    int flat = i * 64 + l;
    int col = flat >> 4, unit = flat & 15;
    uint4 v = *(const uint4*)(Pb + (size_t)(colbase + col) * CD + 384 + unit * 8);
    *(uint4*)(preg + col * 256 + ((unit ^ (col & 15)) << 4)) = v;
  }

  const unsigned short* emp = em + (((size_t)g * 256 * 8 + w) * 64 + l) * 16;
  const size_t emstride = 8 * 64 * 16;

  float Msum[4] = {0.f, 0.f, 0.f, 0.f};

  // epilogue tail: row-max rescale, write A = exp(v - m) to Abuf (2 barriers)
  auto tail = [&](floatx4* a) {
    float mr[4];
#pragma unroll
    for (int r = 0; r < 4; ++r) {
      float m = fmaxf(fmaxf(a[0][r], a[1][r]), fmaxf(a[2][r], a[3][r]));
#pragma unroll
      for (int sh = 1; sh <= 8; sh <<= 1) m = fmaxf(m, __shfl_xor(m, sh));
      mr[r] = m;
    }
    if (l15 == 0) {
#pragma unroll
      for (int r = 0; r < 4; ++r) scratch[(quad * 4 + r) * 8 + w] = mr[r];
    }
    __syncthreads();
#pragma unroll
    for (int r = 0; r < 4; ++r) {
      const floatx4* srow = (const floatx4*)(scratch + (quad * 4 + r) * 8);
      floatx4 s0 = srow[0], s1 = srow[1];
      float m = fmaxf(fmaxf(fmaxf(s0[0], s0[1]), fmaxf(s0[2], s0[3])),
                      fmaxf(fmaxf(s1[0], s1[1]), fmaxf(s1[2], s1[3])));
      Msum[r] += m;
#pragma unroll
      for (int nt = 0; nt < 4; ++nt) {
        float av = __expf(a[nt][r] - m);
        *(unsigned short*)(Abuf + (quad * 4 + r) * 1040 + (colbase + nt * 16 + l15) * 2) = f2bf(av);
      }
    }
    __syncthreads();
  };

  // ---- init (consumes em[0]; fwd also adds start)
  {
    floatx4 a[4];
    const uint4* ep = (const uint4*)emp;
    uint4 e0 = ep[0], e1 = ep[1];
    unsigned eu[8] = {e0.x, e0.y, e0.z, e0.w, e1.x, e1.y, e1.z, e1.w};
#pragma unroll
    for (int nt = 0; nt < 4; ++nt)
#pragma unroll
      for (int r = 0; r < 4; ++r) {
        int j = nt * 4 + r;
        float e = (j & 1) ? bf_hi(eu[j >> 1]) : bf_lo(eu[j >> 1]);
        float s = dir ? 0.f : startv[colbase + nt * 16 + l15];
        a[nt][r] = s + e;
      }
    tail(a);
  }

  const int nsteps = dir ? 256 : 255;
  for (int s = 1; s <= nsteps; ++s) {
    floatx4 acc[4];
#pragma unroll
    for (int nt = 0; nt < 4; ++nt) acc[nt] = zf4();
    const char* abase = Abuf + l15 * 1040 + quad * 16;
#pragma unroll
    for (int kc = 0; kc < 12; ++kc) {
      short8 a = *(const short8*)(abase + kc * 64);
      acc[0] = mfma16(a, Prf[kc][0], acc[0]);
      acc[1] = mfma16(a, Prf[kc][1], acc[1]);
      acc[2] = mfma16(a, Prf[kc][2], acc[2]);
      acc[3] = mfma16(a, Prf[kc][3], acc[3]);
    }
#pragma unroll
    for (int kc = 0; kc < 4; ++kc) {
      short8 a = *(const short8*)(abase + (12 + kc) * 64);
#pragma unroll
      for (int nt = 0; nt < 4; ++nt) {
        int col = nt * 16 + l15;
        int unit = kc * 4 + quad;
        short8 b = *(const short8*)(preg + col * 256 + ((unit ^ (col & 15)) << 4));
        acc[nt] = mfma16(a, b, acc[nt]);
      }
    }
    const bool fin = (s == nsteps);
    const bool addem = (!fin) || (dir == 0);
    unsigned eu[8];
    if (addem) {
      const uint4* ep = (const uint4*)(emp + (size_t)s * emstride);
      uint4 e0 = ep[0], e1 = ep[1];
      eu[0] = e0.x; eu[1] = e0.y; eu[2] = e0.z; eu[3] = e0.w;
      eu[4] = e1.x; eu[5] = e1.y; eu[6] = e1.z; eu[7] = e1.w;
    } else {
#pragma unroll
      for (int i = 0; i < 8; ++i) eu[i] = 0x80008000u;  // bf16 -0.0 pairs -> adds 0
    }
#pragma unroll
    for (int nt = 0; nt < 4; ++nt)
#pragma unroll
      for (int r = 0; r < 4; ++r) {
        int j = nt * 4 + r;
        float e = (j & 1) ? bf_hi(eu[j >> 1]) : bf_lo(eu[j >> 1]);
        acc[nt][r] = __logf(acc[nt][r]) + e;
      }
    if (!fin) {
      tail(acc);
    } else {
      float* dst = dir ? alphaB : alphaF;
#pragma unroll
      for (int nt = 0; nt < 4; ++nt)
#pragma unroll
        for (int r = 0; r < 4; ++r)
          dst[(q * 16 + quad * 4 + r) * CD + colbase + nt * 16 + l15] = acc[nt][r] + Msum[r];
    }
  }
}

// ---------------- meet in the middle: evidence = sum_n lse_c(aF + aB) ----------------
__global__ void k_meet(const float* __restrict__ aF, const float* __restrict__ aB,
                       float* __restrict__ out) {
  __shared__ float wsum[8];
  int tid = threadIdx.x, w = tid >> 6, l = tid & 63;
  float ev = 0.f;
  for (int i = 0; i < 8; ++i) {
    int n = w * 8 + i;
    float x[8];
    float m = -1e30f;
#pragma unroll
    for (int k = 0; k < 8; ++k) {
      x[k] = aF[n * CD + k * 64 + l] + aB[n * CD + k * 64 + l];
      m = fmaxf(m, x[k]);
    }
#pragma unroll
    for (int sh = 1; sh <= 32; sh <<= 1) m = fmaxf(m, __shfl_xor(m, sh));
    float s = 0.f;
#pragma unroll
    for (int k = 0; k < 8; ++k) s += __expf(x[k] - m);
#pragma unroll
    for (int sh = 1; sh <= 32; sh <<= 1) s += __shfl_xor(s, sh);
    ev += m + __logf(s);
  }
  if (l == 0) wsum[w] = ev;
  __syncthreads();
  if (tid == 0) {
    float tot = 0.f;
    for (int i = 0; i < 8; ++i) tot += wsum[i];
    out[0] = tot;
  }
}

// ---------------- host ----------------
extern "C" void kernel_launch(void* const* d_in, const int* in_sizes, int n_in,
                              void* d_out, int out_size, void* d_ws, size_t ws_size,
                              hipStream_t stream) {
  (void)in_sizes; (void)n_in; (void)out_size;
  const int* text = (const int*)d_in[0];
  const float* s_emb = (const float*)d_in[1];
  const float* s_w = (const float*)d_in[2];
  const float* s_b = (const float*)d_in[3];
  const float* s_rw = (const float*)d_in[4];
  const float* s_rb = (const float*)d_in[5];
  const float* stateE = (const float*)d_in[6];
  const float* nextE = (const float*)d_in[7];
  const float* pretE = (const float*)d_in[8];
  const float* t_rw = (const float*)d_in[9];
  const float* t_rb = (const float*)d_in[10];
  const float* termE = (const float*)d_in[11];
  float* out = (float*)d_out;

  char* ws = (char*)d_ws;
  size_t off = 0;
  auto alloc = [&](size_t bytes) {
    void* p = ws + off;
    off = (off + bytes + 255) & ~(size_t)255;
    return p;
  };
  float* w_start = (float*)alloc(CD * 4);
  float* w_fx = (float*)alloc(HD * 4);
  float* w_fx2 = (float*)alloc(HD * 4);
  unsigned short* w_tlg = (unsigned short*)alloc((size_t)CD * CD * 2);
  unsigned short* w_P = (unsigned short*)alloc((size_t)CD * CD * 2);
  unsigned short* w_PT = (unsigned short*)alloc((size_t)CD * CD * 2);
  float* w_fe = (float*)alloc((size_t)CD * HD * 4);
  unsigned short* w_logT = (unsigned short*)alloc((size_t)VD * CD * 2);
  float* w_part = (float*)alloc((size_t)125 * 1024 * 4);
  float* w_lse = (float*)alloc(CD * 4);
  unsigned short* w_em = (unsigned short*)alloc((size_t)8 * 256 * 512 * 16 * 2);
  float* w_aF = (float*)alloc((size_t)ND * CD * 4);
  float* w_aB = (float*)alloc((size_t)ND * CD * 4);
  if (off > ws_size) return;  // workspace too small; bench will show failure

  hipFuncSetAttribute(reinterpret_cast<const void*>(k_gemm),
                      hipFuncAttributeMaxDynamicSharedMemorySize, GEMM_LDS);
  hipFuncSetAttribute(reinterpret_cast<const void*>(k_scan),
                      hipFuncAttributeMaxDynamicSharedMemorySize, SCAN_LDS);

  k_fx<<<1, 256, 0, stream>>>(s_emb, s_w, s_b, w_fx);
  k_mlp<<<1, 256, 0, stream>>>(w_fx, s_rw, s_rb, w_fx2);
  k_slog<<<1, 256, 0, stream>>>(w_fx2, nextE, w_start);

  k_gemm<<<dim3(4, 4), 512, GEMM_LDS, stream>>>(stateE, nextE, w_tlg, CD);
  k_smrow<<<CD, 256, 0, stream>>>(w_tlg, w_P);
  k_tr<<<dim3(4, 4), 512, 0, stream>>>(w_P, w_PT);

  k_mlp<<<CD, 256, 0, stream>>>(pretE, t_rw, t_rb, w_fe);
  k_gemm<<<dim3(250, 4), 512, GEMM_LDS, stream>>>(termE, w_fe, w_logT, CD);

  k_lsep<<<125, 512, 0, stream>>>(w_logT, w_part);
  k_lsef<<<1, 512, 0, stream>>>(w_part, w_lse);

  k_gather<<<2048, 512, 0, stream>>>(text, w_logT, w_lse, w_em);

  k_scan<<<8, 512, SCAN_LDS, stream>>>(w_P, w_PT, w_em, w_start, w_aF, w_aB);
  k_meet<<<1, 512, 0, stream>>>(w_aF, w_aB, out);
}

// Round 2
// 1003.472 us; speedup vs baseline: 1.3224x; 1.3224x over previous
//
#include <hip/hip_runtime.h>
#include <hip/hip_bf16.h>

#define HD 256
#define CD 512
#define VD 32000
#define ND 64
#define TD 512

typedef __attribute__((ext_vector_type(8))) short short8;
typedef __attribute__((ext_vector_type(4))) float floatx4;

__device__ inline float bf2f(unsigned short u) {
  union { unsigned u; float f; } t; t.u = ((unsigned)u) << 16; return t.f;
}
__device__ inline unsigned short f2bf(float x) {
  union { float f; unsigned u; } t; t.f = x;
  unsigned u = t.u;
  u += 0x7FFFu + ((u >> 16) & 1u);
  return (unsigned short)(u >> 16);
}
__device__ inline float bf_lo(unsigned u) { union { unsigned u; float f; } t; t.u = u << 16; return t.f; }
__device__ inline float bf_hi(unsigned u) { union { unsigned u; float f; } t; t.u = u & 0xFFFF0000u; return t.f; }

__device__ inline floatx4 zf4() { floatx4 v; v[0] = v[1] = v[2] = v[3] = 0.f; return v; }
__device__ inline floatx4 mfma16(short8 a, short8 b, floatx4 c) {
  return __builtin_amdgcn_mfma_f32_16x16x32_bf16(a, b, c, 0, 0, 0);
}
__device__ inline floatx4 mfma8(long long a, long long b, floatx4 c) {
  return __builtin_amdgcn_mfma_f32_16x16x32_fp8_fp8(a, b, c, 0, 0, 0);
}

// ---------------- small start-vector kernels ----------------

__global__ void k_fx(const float* __restrict__ emb, const float* __restrict__ W,
                     const float* __restrict__ b, float* __restrict__ out) {
  __shared__ float e[HD];
  int j = threadIdx.x;
  e[j] = emb[j];
  __syncthreads();
  float a = b[j];
#pragma unroll 4
  for (int i = 0; i < HD; ++i) a += e[i] * W[i * HD + j];
  out[j] = a;
}

// x (rows x 256) -> two ResLayers -> out  (one block per row, 256 threads)
__global__ void k_mlp(const float* __restrict__ inp, const float* __restrict__ rw,
                      const float* __restrict__ rb, float* __restrict__ out) {
  __shared__ float x[HD], h[HD];
  int j = threadIdx.x;
  int row = blockIdx.x;
  x[j] = inp[row * HD + j];
  __syncthreads();
  for (int L = 0; L < 2; ++L) {
    const float* w1 = rw + (size_t)(L * 2 + 0) * HD * HD;
    const float* b1 = rb + (L * 2 + 0) * HD;
    const float* w2 = rw + (size_t)(L * 2 + 1) * HD * HD;
    const float* b2 = rb + (L * 2 + 1) * HD;
    float a = b1[j];
#pragma unroll 4
    for (int i = 0; i < HD; ++i) a += x[i] * w1[i * HD + j];
    a = fmaxf(a, 0.f);
    h[j] = a;
    __syncthreads();
    float o = b2[j];
#pragma unroll 4
    for (int i = 0; i < HD; ++i) o += h[i] * w2[i * HD + j];
    x[j] = x[j] + fmaxf(o, 0.f);
    __syncthreads();
  }
  out[row * HD + j] = x[j];
}

// start logits + log_softmax (1 block, 256 threads)
__global__ void k_slog(const float* __restrict__ fx, const float* __restrict__ nextE,
                       float* __restrict__ startO) {
  __shared__ float x[HD];
  __shared__ float red[4];
  int j = threadIdx.x;
  x[j] = fx[j];
  __syncthreads();
  float lg0 = 0.f, lg1 = 0.f;
#pragma unroll 4
  for (int hh = 0; hh < HD; ++hh) {
    float xv = x[hh];
    lg0 += xv * nextE[j * HD + hh];
    lg1 += xv * nextE[(j + 256) * HD + hh];
  }
  float m = fmaxf(lg0, lg1);
#pragma unroll
  for (int sh = 1; sh <= 32; sh <<= 1) m = fmaxf(m, __shfl_xor(m, sh));
  if ((j & 63) == 0) red[j >> 6] = m;
  __syncthreads();
  m = fmaxf(fmaxf(red[0], red[1]), fmaxf(red[2], red[3]));
  __syncthreads();
  float s = __expf(lg0 - m) + __expf(lg1 - m);
#pragma unroll
  for (int sh = 1; sh <= 32; sh <<= 1) s += __shfl_xor(s, sh);
  if ((j & 63) == 0) red[j >> 6] = s;
  __syncthreads();
  s = red[0] + red[1] + red[2] + red[3];
  float ls = __logf(s);
  startO[j] = lg0 - m - ls;
  startO[j + 256] = lg1 - m - ls;
}

// ---------------- generic NT GEMM (M x 256) x (N x 256)^T -> bf16 out[M][N] ----------------
#define GEMM_LDS (2 * 128 * 528)
__global__ __launch_bounds__(512) void k_gemm(const float* __restrict__ A,
                                              const float* __restrict__ B,
                                              unsigned short* __restrict__ out,
                                              int ldo) {
  extern __shared__ char smem[];
  char* sA = smem;             // [128][528 bytes] bf16, K contiguous
  char* sB = smem + 128 * 528;
  const int tid = threadIdx.x;
  const int mbase = blockIdx.x * 128, nbase = blockIdx.y * 128;
  {
    int row = tid >> 2, seg = tid & 3;
    const float4* srcA = (const float4*)(A + (size_t)(mbase + row) * HD + seg * 64);
    const float4* srcB = (const float4*)(B + (size_t)(nbase + row) * HD + seg * 64);
    uint2* dA = (uint2*)(sA + row * 528 + seg * 128);
    uint2* dB = (uint2*)(sB + row * 528 + seg * 128);
#pragma unroll
    for (int i = 0; i < 16; ++i) {
      float4 va = srcA[i];
      float4 vb = srcB[i];
      dA[i] = make_uint2((unsigned)f2bf(va.x) | ((unsigned)f2bf(va.y) << 16),
                         (unsigned)f2bf(va.z) | ((unsigned)f2bf(va.w) << 16));
      dB[i] = make_uint2((unsigned)f2bf(vb.x) | ((unsigned)f2bf(vb.y) << 16),
                         (unsigned)f2bf(vb.z) | ((unsigned)f2bf(vb.w) << 16));
    }
  }
  __syncthreads();
  const int w = tid >> 6, l = tid & 63, l15 = l & 15, quad = l >> 4;
  floatx4 acc[8];
#pragma unroll
  for (int nt = 0; nt < 8; ++nt) acc[nt] = zf4();
  const char* arow = sA + (w * 16 + l15) * 528 + quad * 16;
  const char* brow = sB + l15 * 528 + quad * 16;
#pragma unroll
  for (int kc = 0; kc < 8; ++kc) {
    short8 a = *(const short8*)(arow + kc * 64);
#pragma unroll
    for (int nt = 0; nt < 8; ++nt) {
      short8 b = *(const short8*)(brow + nt * 16 * 528 + kc * 64);
      acc[nt] = mfma16(a, b, acc[nt]);
    }
  }
#pragma unroll
  for (int nt = 0; nt < 8; ++nt)
#pragma unroll
    for (int r = 0; r < 4; ++r) {
      int m = mbase + w * 16 + quad * 4 + r;
      int n = nbase + nt * 16 + l15;
      out[(size_t)m * ldo + n] = f2bf(acc[nt][r]);
    }
}

// ---------------- transition row-softmax -> P fp8 (x64 scale) ----------------
__global__ void k_smrow(const unsigned short* __restrict__ lg, unsigned char* __restrict__ P8) {
  __shared__ float red[4];
  int row = blockIdx.x, j = threadIdx.x;
  float v0 = bf2f(lg[row * CD + j]);
  float v1 = bf2f(lg[row * CD + 256 + j]);
  float m = fmaxf(v0, v1);
#pragma unroll
  for (int sh = 1; sh <= 32; sh <<= 1) m = fmaxf(m, __shfl_xor(m, sh));
  if ((j & 63) == 0) red[j >> 6] = m;
  __syncthreads();
  m = fmaxf(fmaxf(red[0], red[1]), fmaxf(red[2], red[3]));
  __syncthreads();
  float e0 = __expf(v0 - m), e1 = __expf(v1 - m);
  float s = e0 + e1;
#pragma unroll
  for (int sh = 1; sh <= 32; sh <<= 1) s += __shfl_xor(s, sh);
  if ((j & 63) == 0) red[j >> 6] = s;
  __syncthreads();
  s = red[0] + red[1] + red[2] + red[3];
  float inv = 64.0f / s;   // gamma_P = 64 folded in
  int b0 = __builtin_amdgcn_cvt_pk_fp8_f32(e0 * inv, e0 * inv, 0, false);
  int b1 = __builtin_amdgcn_cvt_pk_fp8_f32(e1 * inv, e1 * inv, 0, false);
  P8[row * CD + j] = (unsigned char)(b0 & 0xff);
  P8[row * CD + 256 + j] = (unsigned char)(b1 & 0xff);
}

// transpose fp8 512x512: P8 -> PT8
__global__ __launch_bounds__(256) void k_tr8(const unsigned char* __restrict__ P,
                                             unsigned char* __restrict__ PT) {
  __shared__ unsigned char t[128][144];
  int rb = blockIdx.x * 128, cb = blockIdx.y * 128;
  int tid = threadIdx.x;
  {
    int r = tid >> 1, h = tid & 1;
    const uint4* src = (const uint4*)(P + (size_t)(rb + r) * CD + cb + h * 64);
    uint4* dst = (uint4*)(&t[r][h * 64]);
#pragma unroll
    for (int i = 0; i < 4; ++i) dst[i] = src[i];
  }
  __syncthreads();
  {
    int c = tid >> 1, h = tid & 1;
    unsigned char buf[64];
#pragma unroll
    for (int i = 0; i < 64; ++i) buf[i] = t[h * 64 + i][c];
    uint4* dst = (uint4*)(PT + (size_t)(cb + c) * CD + rb + h * 64);
    const uint4* s = (const uint4*)buf;
#pragma unroll
    for (int i = 0; i < 4; ++i) dst[i] = s[i];
  }
}

// ---------------- vocab log-sum-exp over columns of logT [V][C] ----------------
__global__ __launch_bounds__(512) void k_lsep(const unsigned short* __restrict__ logT,
                                              float* __restrict__ part) {
  int c = threadIdx.x, b = blockIdx.x;
  const unsigned short* p = logT + (size_t)b * 256 * CD + c;
  float m = -1e30f, s = 0.f;
  for (int i = 0; i < 256; ++i) {
    float v = bf2f(p[(size_t)i * CD]);
    float nm = fmaxf(m, v);
    s = s * __expf(m - nm) + __expf(v - nm);
    m = nm;
  }
  part[b * 1024 + c] = m;
  part[b * 1024 + 512 + c] = s;
}

__global__ void k_lsef(const float* __restrict__ part, float* __restrict__ lse) {
  int c = threadIdx.x;
  float m = -1e30f, s = 0.f;
  for (int i = 0; i < 125; ++i) {
    float mi = part[i * 1024 + c], si = part[i * 1024 + 512 + c];
    float nm = fmaxf(m, mi);
    s = s * __expf(m - nm) + si * __expf(mi - nm);
    m = nm;
  }
  lse[c] = m + __logf(s);
}

// ---------------- gather E = exp(emission log-prob), new acc layout ----------------
// lane holds n = q*16 + l15 ; value j = nt*4+r at c = w*64 + nt*16 + quad*4 + r
__global__ __launch_bounds__(512) void k_gather(const int* __restrict__ text,
                                                const unsigned short* __restrict__ logT,
                                                const float* __restrict__ lse,
                                                unsigned short* __restrict__ em) {
  const int b = blockIdx.x;
  const int g = b >> 8, t = b & 255;
  const int dir = g >> 2, q = g & 3;
  const int tg = dir ? (511 - t) : t;
  const int tid = threadIdx.x, w = tid >> 6, l = tid & 63;
  const int l15 = l & 15, quad = l >> 4;
  const int n = q * 16 + l15;
  const int tok = text[n * TD + tg];
  const unsigned short* row = logT + (size_t)tok * CD;
  unsigned outp[8];
#pragma unroll
  for (int nt = 0; nt < 4; ++nt) {
    int c0 = w * 64 + nt * 16 + quad * 4;
    uint2 rv = *(const uint2*)(row + c0);
    float4 ls = *(const float4*)(lse + c0);
    float E0 = __expf(bf_lo(rv.x) - ls.x);
    float E1 = __expf(bf_hi(rv.x) - ls.y);
    float E2 = __expf(bf_lo(rv.y) - ls.z);
    float E3 = __expf(bf_hi(rv.y) - ls.w);
    outp[nt * 2 + 0] = (unsigned)f2bf(E0) | ((unsigned)f2bf(E1) << 16);
    outp[nt * 2 + 1] = (unsigned)f2bf(E2) | ((unsigned)f2bf(E3) << 16);
  }
  uint4* dst = (uint4*)(em + (((size_t)b * 8 + w) * 64 + l) * 16);
  dst[0] = make_uint4(outp[0], outp[1], outp[2], outp[3]);
  dst[1] = make_uint4(outp[4], outp[5], outp[6], outp[7]);
}

// ---------------- the scan: 8 blocks (4 fwd + 4 bwd), 16 seqs each ----------------
// P resident entirely in registers as fp8 A-operand fragments; alpha is the
// B-operand staged in LDS; linear-domain with per-seq max rescale.
__global__ __launch_bounds__(512, 2) void k_scan(const unsigned char* __restrict__ P8,
                                                 const unsigned char* __restrict__ PT8,
                                                 const unsigned short* __restrict__ em,
                                                 const float* __restrict__ startv,
                                                 float* __restrict__ alphaF,
                                                 float* __restrict__ alphaB) {
  __shared__ unsigned char Abuf[16 * 528];   // [seq n][c fp8], stride 528
  __shared__ float scratch[16 * 8];          // [l15][wave]
  const int g = blockIdx.x, dir = g >> 2, q = g & 3;
  const int tid = threadIdx.x, w = tid >> 6, l = tid & 63;
  const int l15 = l & 15, quad = l >> 4;
  const int colbase = w * 64;
  const unsigned char* Pb = dir ? P8 : PT8;  // [out state][src state], x64-scaled fp8

  // A-operand fragments: A[m = out-state local (l15)][k = src state]
  long long Prf[16][4];
#pragma unroll
  for (int kc = 0; kc < 16; ++kc)
#pragma unroll
    for (int nt = 0; nt < 4; ++nt)
      Prf[kc][nt] = *(const long long*)(Pb + (size_t)(colbase + nt * 16 + l15) * CD + kc * 32 + quad * 8);

  const unsigned short* emp = em + (((size_t)g * 256 * 8 + w) * 64 + l) * 16;
  const size_t emstride = 8 * 64 * 16;

  float Msum = 0.f;
  const float LGAP = 6.93147181f;  // log(16*64)
  const float LGA = 2.77258872f;   // log 16
  const float LGP = 4.15888308f;   // log 64

  auto tail = [&](float* v, float sub) {
    float m = v[0];
#pragma unroll
    for (int j = 1; j < 16; ++j) m = fmaxf(m, v[j]);
    m = fmaxf(m, __shfl_xor(m, 16));
    m = fmaxf(m, __shfl_xor(m, 32));
    if (quad == 0) scratch[l15 * 8 + w] = m;
    __syncthreads();
    const floatx4* sr = (const floatx4*)(scratch + l15 * 8);
    floatx4 s0 = sr[0], s1 = sr[1];
    m = fmaxf(fmaxf(fmaxf(s0[0], s0[1]), fmaxf(s0[2], s0[3])),
              fmaxf(fmaxf(s1[0], s1[1]), fmaxf(s1[2], s1[3])));
    float inv = 16.0f / m;  // gamma_A = 16
    Msum += __logf(m) - sub;
#pragma unroll
    for (int nt = 0; nt < 4; ++nt) {
      int pk = __builtin_amdgcn_cvt_pk_fp8_f32(v[nt * 4 + 0] * inv, v[nt * 4 + 1] * inv, 0, false);
      pk = __builtin_amdgcn_cvt_pk_fp8_f32(v[nt * 4 + 2] * inv, v[nt * 4 + 3] * inv, pk, true);
    *(int*)&Abuf[l15 * 528 + colbase + nt * 16 + quad * 4] = pk;
    }
    __syncthreads();
  };

  // ---- init: A0 = exp(start) * E0 (fwd) or E0 (bwd)
  {
    const uint4* ep = (const uint4*)emp;
    uint4 e0 = ep[0], e1 = ep[1];
    unsigned eu[8] = {e0.x, e0.y, e0.z, e0.w, e1.x, e1.y, e1.z, e1.w};
    float v[16];
#pragma unroll
    for (int nt = 0; nt < 4; ++nt)
#pragma unroll
      for (int r = 0; r < 4; ++r) {
        int j = nt * 4 + r;
        float E = (j & 1) ? bf_hi(eu[j >> 1]) : bf_lo(eu[j >> 1]);
        float st = dir ? 1.f : __expf(startv[colbase + nt * 16 + quad * 4 + r]);
        v[j] = st * E;
      }
    tail(v, LGA);
  }

  const int nsteps = dir ? 256 : 255;
  for (int s = 1; s <= nsteps; ++s) {
    floatx4 acc[4];
#pragma unroll
    for (int nt = 0; nt < 4; ++nt) acc[nt] = zf4();
#pragma unroll
    for (int kc = 0; kc < 16; ++kc) {
      long long a = *(const long long*)&Abuf[l15 * 528 + kc * 32 + quad * 8];
      acc[0] = mfma8(Prf[kc][0], a, acc[0]);
      acc[1] = mfma8(Prf[kc][1], a, acc[1]);
      acc[2] = mfma8(Prf[kc][2], a, acc[2]);
      acc[3] = mfma8(Prf[kc][3], a, acc[3]);
    }
    const bool fin = (s == nsteps);
    const bool addem = (!fin) || (dir == 0);
    unsigned eu[8];
    if (addem) {
      const uint4* ep = (const uint4*)(emp + (size_t)s * emstride);
      uint4 e0 = ep[0], e1 = ep[1];
      eu[0] = e0.x; eu[1] = e0.y; eu[2] = e0.z; eu[3] = e0.w;
      eu[4] = e1.x; eu[5] = e1.y; eu[6] = e1.z; eu[7] = e1.w;
    } else {
#pragma unroll
      for (int i = 0; i < 8; ++i) eu[i] = 0x3F803F80u;  // bf16 1.0 pairs
    }
    float v[16];
#pragma unroll
    for (int nt = 0; nt < 4; ++nt)
#pragma unroll
      for (int r = 0; r < 4; ++r) {
        int j = nt * 4 + r;
        float E = (j & 1) ? bf_hi(eu[j >> 1]) : bf_lo(eu[j >> 1]);
        v[j] = acc[nt][r] * E;
      }
    if (!fin) {
      tail(v, LGAP);
    } else {
      float* dst = dir ? alphaB : alphaF;
#pragma unroll
      for (int nt = 0; nt < 4; ++nt) {
        float4 o;
        o.x = __logf(v[nt * 4 + 0]) + Msum - LGP;
        o.y = __logf(v[nt * 4 + 1]) + Msum - LGP;
        o.z = __logf(v[nt * 4 + 2]) + Msum - LGP;
        o.w = __logf(v[nt * 4 + 3]) + Msum - LGP;
        *(float4*)&dst[(size_t)(q * 16 + l15) * CD + colbase + nt * 16 + quad * 4] = o;
      }
    }
  }
}

// ---------------- meet in the middle: evidence = sum_n lse_c(aF + aB) ----------------
__global__ void k_meet(const float* __restrict__ aF, const float* __restrict__ aB,
                       float* __restrict__ out) {
  __shared__ float wsum[8];
  int tid = threadIdx.x, w = tid >> 6, l = tid & 63;
  float ev = 0.f;
  for (int i = 0; i < 8; ++i) {
    int n = w * 8 + i;
    float x[8];
    float m = -1e30f;
#pragma unroll
    for (int k = 0; k < 8; ++k) {
      x[k] = aF[n * CD + k * 64 + l] + aB[n * CD + k * 64 + l];
      m = fmaxf(m, x[k]);
    }
#pragma unroll
    for (int sh = 1; sh <= 32; sh <<= 1) m = fmaxf(m, __shfl_xor(m, sh));
    float s = 0.f;
#pragma unroll
    for (int k = 0; k < 8; ++k) s += __expf(x[k] - m);
#pragma unroll
    for (int sh = 1; sh <= 32; sh <<= 1) s += __shfl_xor(s, sh);
    ev += m + __logf(s);
  }
  if (l == 0) wsum[w] = ev;
  __syncthreads();
  if (tid == 0) {
    float tot = 0.f;
    for (int i = 0; i < 8; ++i) tot += wsum[i];
    out[0] = tot;
  }
}

// ---------------- host ----------------
extern "C" void kernel_launch(void* const* d_in, const int* in_sizes, int n_in,
                              void* d_out, int out_size, void* d_ws, size_t ws_size,
                              hipStream_t stream) {
  (void)in_sizes; (void)n_in; (void)out_size;
  const int* text = (const int*)d_in[0];
  const float* s_emb = (const float*)d_in[1];
  const float* s_w = (const float*)d_in[2];
  const float* s_b = (const float*)d_in[3];
  const float* s_rw = (const float*)d_in[4];
  const float* s_rb = (const float*)d_in[5];
  const float* stateE = (const float*)d_in[6];
  const float* nextE = (const float*)d_in[7];
  const float* pretE = (const float*)d_in[8];
  const float* t_rw = (const float*)d_in[9];
  const float* t_rb = (const float*)d_in[10];
  const float* termE = (const float*)d_in[11];
  float* out = (float*)d_out;

  char* ws = (char*)d_ws;
  size_t off = 0;
  auto alloc = [&](size_t bytes) {
    void* p = ws + off;
    off = (off + bytes + 255) & ~(size_t)255;
    return p;
  };
  float* w_start = (float*)alloc(CD * 4);
  float* w_fx = (float*)alloc(HD * 4);
  float* w_fx2 = (float*)alloc(HD * 4);
  unsigned short* w_tlg = (unsigned short*)alloc((size_t)CD * CD * 2);
  unsigned char* w_P8 = (unsigned char*)alloc((size_t)CD * CD);
  unsigned char* w_PT8 = (unsigned char*)alloc((size_t)CD * CD);
  float* w_fe = (float*)alloc((size_t)CD * HD * 4);
  unsigned short* w_logT = (unsigned short*)alloc((size_t)VD * CD * 2);
  float* w_part = (float*)alloc((size_t)125 * 1024 * 4);
  float* w_lse = (float*)alloc(CD * 4);
  unsigned short* w_em = (unsigned short*)alloc((size_t)8 * 256 * 512 * 16 * 2);
  float* w_aF = (float*)alloc((size_t)ND * CD * 4);
  float* w_aB = (float*)alloc((size_t)ND * CD * 4);
  if (off > ws_size) return;

  hipFuncSetAttribute(reinterpret_cast<const void*>(k_gemm),
                      hipFuncAttributeMaxDynamicSharedMemorySize, GEMM_LDS);

  k_fx<<<1, 256, 0, stream>>>(s_emb, s_w, s_b, w_fx);
  k_mlp<<<1, 256, 0, stream>>>(w_fx, s_rw, s_rb, w_fx2);
  k_slog<<<1, 256, 0, stream>>>(w_fx2, nextE, w_start);

  k_gemm<<<dim3(4, 4), 512, GEMM_LDS, stream>>>(stateE, nextE, w_tlg, CD);
  k_smrow<<<CD, 256, 0, stream>>>(w_tlg, w_P8);
  k_tr8<<<dim3(4, 4), 256, 0, stream>>>(w_P8, w_PT8);

  k_mlp<<<CD, 256, 0, stream>>>(pretE, t_rw, t_rb, w_fe);
  k_gemm<<<dim3(250, 4), 512, GEMM_LDS, stream>>>(termE, w_fe, w_logT, CD);

  k_lsep<<<125, 512, 0, stream>>>(w_logT, w_part);
  k_lsef<<<1, 512, 0, stream>>>(w_part, w_lse);

  k_gather<<<2048, 512, 0, stream>>>(text, w_logT, w_lse, w_em);

  k_scan<<<8, 512, 0, stream>>>(w_P8, w_PT8, w_em, w_start, w_aF, w_aB);
  k_meet<<<1, 512, 0, stream>>>(w_aF, w_aB, out);
}

// Round 3
// 848.051 us; speedup vs baseline: 1.5648x; 1.1833x over previous
//
#include <hip/hip_runtime.h>
#include <hip/hip_bf16.h>

#define HD 256
#define CD 512
#define VD 32000
#define ND 64
#define TD 512

typedef __attribute__((ext_vector_type(8))) short short8;
typedef __attribute__((ext_vector_type(4))) float floatx4;
typedef __attribute__((ext_vector_type(8))) int int32x8;

__device__ inline float bf2f(unsigned short u) {
  union { unsigned u; float f; } t; t.u = ((unsigned)u) << 16; return t.f;
}
__device__ inline unsigned short f2bf(float x) {
  union { float f; unsigned u; } t; t.f = x;
  unsigned u = t.u;
  u += 0x7FFFu + ((u >> 16) & 1u);
  return (unsigned short)(u >> 16);
}
__device__ inline float bf_lo(unsigned u) { union { unsigned u; float f; } t; t.u = u << 16; return t.f; }
__device__ inline float bf_hi(unsigned u) { union { unsigned u; float f; } t; t.u = u & 0xFFFF0000u; return t.f; }

__device__ inline floatx4 zf4() { floatx4 v; v[0] = v[1] = v[2] = v[3] = 0.f; return v; }
__device__ inline floatx4 mfma16(short8 a, short8 b, floatx4 c) {
  return __builtin_amdgcn_mfma_f32_16x16x32_bf16(a, b, c, 0, 0, 0);
}
// MX-scaled fp8 MFMA, scales pinned to 1.0 (E8M0 bias 127 = 0x7F)
__device__ inline floatx4 mfma_mx(int32x8 a, int32x8 b, floatx4 c) {
  return __builtin_amdgcn_mfma_scale_f32_16x16x128_f8f6f4(
      a, b, c, 0, 0, 0, 0x7F7F7F7F, 0, 0x7F7F7F7F);
}

// ---------------- small start-vector kernels ----------------

__global__ void k_fx(const float* __restrict__ emb, const float* __restrict__ W,
                     const float* __restrict__ b, float* __restrict__ out) {
  __shared__ float e[HD];
  int j = threadIdx.x;
  e[j] = emb[j];
  __syncthreads();
  float a = b[j];
#pragma unroll 4
  for (int i = 0; i < HD; ++i) a += e[i] * W[i * HD + j];
  out[j] = a;
}

// x (rows x 256) -> two ResLayers -> out  (one block per row, 256 threads)
__global__ void k_mlp(const float* __restrict__ inp, const float* __restrict__ rw,
                      const float* __restrict__ rb, float* __restrict__ out) {
  __shared__ float x[HD], h[HD];
  int j = threadIdx.x;
  int row = blockIdx.x;
  x[j] = inp[row * HD + j];
  __syncthreads();
  for (int L = 0; L < 2; ++L) {
    const float* w1 = rw + (size_t)(L * 2 + 0) * HD * HD;
    const float* b1 = rb + (L * 2 + 0) * HD;
    const float* w2 = rw + (size_t)(L * 2 + 1) * HD * HD;
    const float* b2 = rb + (L * 2 + 1) * HD;
    float a = b1[j];
#pragma unroll 4
    for (int i = 0; i < HD; ++i) a += x[i] * w1[i * HD + j];
    a = fmaxf(a, 0.f);
    h[j] = a;
    __syncthreads();
    float o = b2[j];
#pragma unroll 4
    for (int i = 0; i < HD; ++i) o += h[i] * w2[i * HD + j];
    x[j] = x[j] + fmaxf(o, 0.f);
    __syncthreads();
  }
  out[row * HD + j] = x[j];
}

// start logits + log_softmax (1 block, 256 threads)
__global__ void k_slog(const float* __restrict__ fx, const float* __restrict__ nextE,
                       float* __restrict__ startO) {
  __shared__ float x[HD];
  __shared__ float red[4];
  int j = threadIdx.x;
  x[j] = fx[j];
  __syncthreads();
  float lg0 = 0.f, lg1 = 0.f;
#pragma unroll 4
  for (int hh = 0; hh < HD; ++hh) {
    float xv = x[hh];
    lg0 += xv * nextE[j * HD + hh];
    lg1 += xv * nextE[(j + 256) * HD + hh];
  }
  float m = fmaxf(lg0, lg1);
#pragma unroll
  for (int sh = 1; sh <= 32; sh <<= 1) m = fmaxf(m, __shfl_xor(m, sh));
  if ((j & 63) == 0) red[j >> 6] = m;
  __syncthreads();
  m = fmaxf(fmaxf(red[0], red[1]), fmaxf(red[2], red[3]));
  __syncthreads();
  float s = __expf(lg0 - m) + __expf(lg1 - m);
#pragma unroll
  for (int sh = 1; sh <= 32; sh <<= 1) s += __shfl_xor(s, sh);
  if ((j & 63) == 0) red[j >> 6] = s;
  __syncthreads();
  s = red[0] + red[1] + red[2] + red[3];
  float ls = __logf(s);
  startO[j] = lg0 - m - ls;
  startO[j + 256] = lg1 - m - ls;
}

// ---------------- generic NT GEMM (M x 256) x (N x 256)^T -> bf16 out[M][N] ----------------
#define GEMM_LDS (2 * 128 * 528)
__global__ __launch_bounds__(512) void k_gemm(const float* __restrict__ A,
                                              const float* __restrict__ B,
                                              unsigned short* __restrict__ out,
                                              int ldo) {
  extern __shared__ char smem[];
  char* sA = smem;             // [128][528 bytes] bf16, K contiguous
  char* sB = smem + 128 * 528;
  const int tid = threadIdx.x;
  const int mbase = blockIdx.x * 128, nbase = blockIdx.y * 128;
  {
    int row = tid >> 2, seg = tid & 3;
    const float4* srcA = (const float4*)(A + (size_t)(mbase + row) * HD + seg * 64);
    const float4* srcB = (const float4*)(B + (size_t)(nbase + row) * HD + seg * 64);
    uint2* dA = (uint2*)(sA + row * 528 + seg * 128);
    uint2* dB = (uint2*)(sB + row * 528 + seg * 128);
#pragma unroll
    for (int i = 0; i < 16; ++i) {
      float4 va = srcA[i];
      float4 vb = srcB[i];
      dA[i] = make_uint2((unsigned)f2bf(va.x) | ((unsigned)f2bf(va.y) << 16),
                         (unsigned)f2bf(va.z) | ((unsigned)f2bf(va.w) << 16));
      dB[i] = make_uint2((unsigned)f2bf(vb.x) | ((unsigned)f2bf(vb.y) << 16),
                         (unsigned)f2bf(vb.z) | ((unsigned)f2bf(vb.w) << 16));
    }
  }
  __syncthreads();
  const int w = tid >> 6, l = tid & 63, l15 = l & 15, quad = l >> 4;
  floatx4 acc[8];
#pragma unroll
  for (int nt = 0; nt < 8; ++nt) acc[nt] = zf4();
  const char* arow = sA + (w * 16 + l15) * 528 + quad * 16;
  const char* brow = sB + l15 * 528 + quad * 16;
#pragma unroll
  for (int kc = 0; kc < 8; ++kc) {
    short8 a = *(const short8*)(arow + kc * 64);
#pragma unroll
    for (int nt = 0; nt < 8; ++nt) {
      short8 b = *(const short8*)(brow + nt * 16 * 528 + kc * 64);
      acc[nt] = mfma16(a, b, acc[nt]);
    }
  }
#pragma unroll
  for (int nt = 0; nt < 8; ++nt)
#pragma unroll
    for (int r = 0; r < 4; ++r) {
      int m = mbase + w * 16 + quad * 4 + r;
      int n = nbase + nt * 16 + l15;
      out[(size_t)m * ldo + n] = f2bf(acc[nt][r]);
    }
}

// ---------------- transition row-softmax -> P fp8 (x64 scale) ----------------
__global__ void k_smrow(const unsigned short* __restrict__ lg, unsigned char* __restrict__ P8) {
  __shared__ float red[4];
  int row = blockIdx.x, j = threadIdx.x;
  float v0 = bf2f(lg[row * CD + j]);
  float v1 = bf2f(lg[row * CD + 256 + j]);
  float m = fmaxf(v0, v1);
#pragma unroll
  for (int sh = 1; sh <= 32; sh <<= 1) m = fmaxf(m, __shfl_xor(m, sh));
  if ((j & 63) == 0) red[j >> 6] = m;
  __syncthreads();
  m = fmaxf(fmaxf(red[0], red[1]), fmaxf(red[2], red[3]));
  __syncthreads();
  float e0 = __expf(v0 - m), e1 = __expf(v1 - m);
  float s = e0 + e1;
#pragma unroll
  for (int sh = 1; sh <= 32; sh <<= 1) s += __shfl_xor(s, sh);
  if ((j & 63) == 0) red[j >> 6] = s;
  __syncthreads();
  s = red[0] + red[1] + red[2] + red[3];
  float inv = 64.0f / s;   // gamma_P = 64 folded in
  int b0 = __builtin_amdgcn_cvt_pk_fp8_f32(e0 * inv, e0 * inv, 0, false);
  int b1 = __builtin_amdgcn_cvt_pk_fp8_f32(e1 * inv, e1 * inv, 0, false);
  P8[row * CD + j] = (unsigned char)(b0 & 0xff);
  P8[row * CD + 256 + j] = (unsigned char)(b1 & 0xff);
}

// transpose fp8 512x512: P8 -> PT8
__global__ __launch_bounds__(256) void k_tr8(const unsigned char* __restrict__ P,
                                             unsigned char* __restrict__ PT) {
  __shared__ unsigned char t[128][144];
  int rb = blockIdx.x * 128, cb = blockIdx.y * 128;
  int tid = threadIdx.x;
  {
    int r = tid >> 1, h = tid & 1;
    const uint4* src = (const uint4*)(P + (size_t)(rb + r) * CD + cb + h * 64);
    uint4* dst = (uint4*)(&t[r][h * 64]);
#pragma unroll
    for (int i = 0; i < 4; ++i) dst[i] = src[i];
  }
  __syncthreads();
  {
    int c = tid >> 1, h = tid & 1;
    unsigned char buf[64];
#pragma unroll
    for (int i = 0; i < 64; ++i) buf[i] = t[h * 64 + i][c];
    uint4* dst = (uint4*)(PT + (size_t)(cb + c) * CD + rb + h * 64);
    const uint4* s = (const uint4*)buf;
#pragma unroll
    for (int i = 0; i < 4; ++i) dst[i] = s[i];
  }
}

// ---------------- vocab log-sum-exp over columns of logT [V][C] ----------------
__global__ __launch_bounds__(512) void k_lsep(const unsigned short* __restrict__ logT,
                                              float* __restrict__ part) {
  int c = threadIdx.x, b = blockIdx.x;
  const unsigned short* p = logT + (size_t)b * 256 * CD + c;
  float m = -1e30f, s = 0.f;
  for (int i = 0; i < 256; ++i) {
    float v = bf2f(p[(size_t)i * CD]);
    float nm = fmaxf(m, v);
    s = s * __expf(m - nm) + __expf(v - nm);
    m = nm;
  }
  part[b * 1024 + c] = m;
  part[b * 1024 + 512 + c] = s;
}

__global__ void k_lsef(const float* __restrict__ part, float* __restrict__ lse) {
  int c = threadIdx.x;
  float m = -1e30f, s = 0.f;
  for (int i = 0; i < 125; ++i) {
    float mi = part[i * 1024 + c], si = part[i * 1024 + 512 + c];
    float nm = fmaxf(m, mi);
    s = s * __expf(m - nm) + si * __expf(mi - nm);
    m = nm;
  }
  lse[c] = m + __logf(s);
}

// ---------------- gather E = exp(emission log-prob) ----------------
// lane holds n = q*16 + l15 ; value j = nt*4+r at c = w*64 + nt*16 + quad*4 + r
__global__ __launch_bounds__(512) void k_gather(const int* __restrict__ text,
                                                const unsigned short* __restrict__ logT,
                                                const float* __restrict__ lse,
                                                unsigned short* __restrict__ em) {
  const int b = blockIdx.x;
  const int g = b >> 8, t = b & 255;
  const int dir = g >> 2, q = g & 3;
  const int tg = dir ? (511 - t) : t;
  const int tid = threadIdx.x, w = tid >> 6, l = tid & 63;
  const int l15 = l & 15, quad = l >> 4;
  const int n = q * 16 + l15;
  const int tok = text[n * TD + tg];
  const unsigned short* row = logT + (size_t)tok * CD;
  unsigned outp[8];
#pragma unroll
  for (int nt = 0; nt < 4; ++nt) {
    int c0 = w * 64 + nt * 16 + quad * 4;
    uint2 rv = *(const uint2*)(row + c0);
    float4 ls = *(const float4*)(lse + c0);
    float E0 = __expf(bf_lo(rv.x) - ls.x);
    float E1 = __expf(bf_hi(rv.x) - ls.y);
    float E2 = __expf(bf_lo(rv.y) - ls.z);
    float E3 = __expf(bf_hi(rv.y) - ls.w);
    outp[nt * 2 + 0] = (unsigned)f2bf(E0) | ((unsigned)f2bf(E1) << 16);
    outp[nt * 2 + 1] = (unsigned)f2bf(E2) | ((unsigned)f2bf(E3) << 16);
  }
  uint4* dst = (uint4*)(em + (((size_t)b * 8 + w) * 64 + l) * 16);
  dst[0] = make_uint4(outp[0], outp[1], outp[2], outp[3]);
  dst[1] = make_uint4(outp[4], outp[5], outp[6], outp[7]);
}

// ---------------- the scan: 8 blocks (4 fwd + 4 bwd), 16 seqs each ----------------
// P resident in registers as fp8 A-operand fragments for mfma_scale 16x16x128;
// alpha is the B-operand staged in XOR-swizzled LDS; linear domain, per-seq
// max rescale each step.
__global__ __launch_bounds__(512, 2) void k_scan(const unsigned char* __restrict__ P8,
                                                 const unsigned char* __restrict__ PT8,
                                                 const unsigned short* __restrict__ em,
                                                 const float* __restrict__ startv,
                                                 float* __restrict__ alphaF,
                                                 float* __restrict__ alphaB) {
  __shared__ unsigned char Abuf[16 * 512];   // [seq][k fp8], 16B-unit XOR swizzle by (seq&7)
  __shared__ float scratch[16 * 8];          // [l15][wave]
  const int g = blockIdx.x, dir = g >> 2, q = g & 3;
  const int tid = threadIdx.x, w = tid >> 6, l = tid & 63;
  const int l15 = l & 15, quad = l >> 4;
  const int s7 = l15 & 7;
  const int colbase = w * 64;
  const unsigned char* Pb = dir ? P8 : PT8;  // [out state][src state], x64-scaled fp8

  // A-operand fragments: A[m = out-state local l15][k = kc*128 + quad*32 + j]
  int32x8 Prf[4][4];
#pragma unroll
  for (int kc = 0; kc < 4; ++kc)
#pragma unroll
    for (int mt = 0; mt < 4; ++mt) {
      const uint4* p = (const uint4*)(Pb + (size_t)(colbase + mt * 16 + l15) * CD + kc * 128 + quad * 32);
      uint4 x0 = p[0], x1 = p[1];
      Prf[kc][mt] = (int32x8){(int)x0.x, (int)x0.y, (int)x0.z, (int)x0.w,
                              (int)x1.x, (int)x1.y, (int)x1.z, (int)x1.w};
    }

  // per-lane swizzled LDS addresses
  unsigned char* wr[4];
#pragma unroll
  for (int mt = 0; mt < 4; ++mt)
    wr[mt] = Abuf + l15 * 512 + (((w * 4 + mt) ^ s7) << 4) + quad * 4;
  const unsigned char* rdrow = Abuf + l15 * 512;

  const unsigned short* emp = em + (((size_t)g * 256 * 8 + w) * 64 + l) * 16;
  const size_t emstride = 8 * 64 * 16;

  float Msum = 0.f;
  const float LGAP = 6.93147181f;  // log(16*64)
  const float LGA = 2.77258872f;   // log 16
  const float LGP = 4.15888308f;   // log 64

  auto tail = [&](float* v, float sub) {
    float m = v[0];
#pragma unroll
    for (int j = 1; j < 16; ++j) m = fmaxf(m, v[j]);
    m = fmaxf(m, __shfl_xor(m, 16));
    m = fmaxf(m, __shfl_xor(m, 32));
    if (quad == 0) scratch[l15 * 8 + w] = m;
    __syncthreads();
    const floatx4* sr = (const floatx4*)(scratch + l15 * 8);
    floatx4 s0 = sr[0], s1 = sr[1];
    m = fmaxf(fmaxf(fmaxf(s0[0], s0[1]), fmaxf(s0[2], s0[3])),
              fmaxf(fmaxf(s1[0], s1[1]), fmaxf(s1[2], s1[3])));
    float inv = __builtin_amdgcn_rcpf(m) * 16.0f;  // gamma_A = 16
    Msum += __logf(m) - sub;
#pragma unroll
    for (int mt = 0; mt < 4; ++mt) {
      int pk = __builtin_amdgcn_cvt_pk_fp8_f32(v[mt * 4 + 0] * inv, v[mt * 4 + 1] * inv, 0, false);
      pk = __builtin_amdgcn_cvt_pk_fp8_f32(v[mt * 4 + 2] * inv, v[mt * 4 + 3] * inv, pk, true);
      *(int*)wr[mt] = pk;
    }
    __syncthreads();
  };

  // ---- init: A0 = exp(start) * E0 (fwd) or E0 (bwd)
  {
    const uint4* ep = (const uint4*)emp;
    uint4 e0 = ep[0], e1 = ep[1];
    unsigned eu[8] = {e0.x, e0.y, e0.z, e0.w, e1.x, e1.y, e1.z, e1.w};
    float v[16];
#pragma unroll
    for (int mt = 0; mt < 4; ++mt)
#pragma unroll
      for (int r = 0; r < 4; ++r) {
        int j = mt * 4 + r;
        float E = (j & 1) ? bf_hi(eu[j >> 1]) : bf_lo(eu[j >> 1]);
        float st = dir ? 1.f : __expf(startv[colbase + mt * 16 + quad * 4 + r]);
        v[j] = st * E;
      }
    tail(v, LGA);
  }

  const int nsteps = dir ? 256 : 255;
  // current-step em (for s=1)
  uint4 ec0, ec1;
  {
    const uint4* ep = (const uint4*)(emp + emstride);
    ec0 = ep[0]; ec1 = ep[1];
  }
  for (int s = 1; s <= nsteps; ++s) {
    // B fragments for the 4 K-chunks (alpha of prev step, swizzled LDS)
    int32x8 bfr[4];
#pragma unroll
    for (int kc = 0; kc < 4; ++kc) {
      int u0 = kc * 8 + quad * 2;
      uint4 x0 = *(const uint4*)(rdrow + (((u0 + 0) ^ s7) << 4));
      uint4 x1 = *(const uint4*)(rdrow + (((u0 + 1) ^ s7) << 4));
      bfr[kc] = (int32x8){(int)x0.x, (int)x0.y, (int)x0.z, (int)x0.w,
                          (int)x1.x, (int)x1.y, (int)x1.z, (int)x1.w};
    }
    // prefetch next step's em while MFMAs run
    uint4 en0, en1;
    const bool fin = (s == nsteps);
    if (!fin) {
      const uint4* ep = (const uint4*)(emp + (size_t)(s + 1) * emstride);
      en0 = ep[0]; en1 = ep[1];
    }
    floatx4 acc[4];
#pragma unroll
    for (int mt = 0; mt < 4; ++mt) acc[mt] = zf4();
#pragma unroll
    for (int kc = 0; kc < 4; ++kc) {
      acc[0] = mfma_mx(Prf[kc][0], bfr[kc], acc[0]);
      acc[1] = mfma_mx(Prf[kc][1], bfr[kc], acc[1]);
      acc[2] = mfma_mx(Prf[kc][2], bfr[kc], acc[2]);
      acc[3] = mfma_mx(Prf[kc][3], bfr[kc], acc[3]);
    }
    const bool addem = (!fin) || (dir == 0);
    unsigned eu[8];
    if (addem) {
      eu[0] = ec0.x; eu[1] = ec0.y; eu[2] = ec0.z; eu[3] = ec0.w;
      eu[4] = ec1.x; eu[5] = ec1.y; eu[6] = ec1.z; eu[7] = ec1.w;
    } else {
#pragma unroll
      for (int i = 0; i < 8; ++i) eu[i] = 0x3F803F80u;  // bf16 1.0 pairs
    }
    float v[16];
#pragma unroll
    for (int mt = 0; mt < 4; ++mt)
#pragma unroll
      for (int r = 0; r < 4; ++r) {
        int j = mt * 4 + r;
        float E = (j & 1) ? bf_hi(eu[j >> 1]) : bf_lo(eu[j >> 1]);
        v[j] = acc[mt][r] * E;
      }
    if (!fin) {
      tail(v, LGAP);
      ec0 = en0; ec1 = en1;
    } else {
      float* dst = dir ? alphaB : alphaF;
#pragma unroll
      for (int mt = 0; mt < 4; ++mt) {
        float4 o;
        o.x = __logf(v[mt * 4 + 0]) + Msum - LGP;
        o.y = __logf(v[mt * 4 + 1]) + Msum - LGP;
        o.z = __logf(v[mt * 4 + 2]) + Msum - LGP;
        o.w = __logf(v[mt * 4 + 3]) + Msum - LGP;
        *(float4*)&dst[(size_t)(q * 16 + l15) * CD + colbase + mt * 16 + quad * 4] = o;
      }
    }
  }
}

// ---------------- meet in the middle: evidence = sum_n lse_c(aF + aB) ----------------
__global__ void k_meet(const float* __restrict__ aF, const float* __restrict__ aB,
                       float* __restrict__ out) {
  __shared__ float wsum[8];
  int tid = threadIdx.x, w = tid >> 6, l = tid & 63;
  float ev = 0.f;
  for (int i = 0; i < 8; ++i) {
    int n = w * 8 + i;
    float x[8];
    float m = -1e30f;
#pragma unroll
    for (int k = 0; k < 8; ++k) {
      x[k] = aF[n * CD + k * 64 + l] + aB[n * CD + k * 64 + l];
      m = fmaxf(m, x[k]);
    }
#pragma unroll
    for (int sh = 1; sh <= 32; sh <<= 1) m = fmaxf(m, __shfl_xor(m, sh));
    float s = 0.f;
#pragma unroll
    for (int k = 0; k < 8; ++k) s += __expf(x[k] - m);
#pragma unroll
    for (int sh = 1; sh <= 32; sh <<= 1) s += __shfl_xor(s, sh);
    ev += m + __logf(s);
  }
  if (l == 0) wsum[w] = ev;
  __syncthreads();
  if (tid == 0) {
    float tot = 0.f;
    for (int i = 0; i < 8; ++i) tot += wsum[i];
    out[0] = tot;
  }
}

// ---------------- host ----------------
extern "C" void kernel_launch(void* const* d_in, const int* in_sizes, int n_in,
                              void* d_out, int out_size, void* d_ws, size_t ws_size,
                              hipStream_t stream) {
  (void)in_sizes; (void)n_in; (void)out_size;
  const int* text = (const int*)d_in[0];
  const float* s_emb = (const float*)d_in[1];
  const float* s_w = (const float*)d_in[2];
  const float* s_b = (const float*)d_in[3];
  const float* s_rw = (const float*)d_in[4];
  const float* s_rb = (const float*)d_in[5];
  const float* stateE = (const float*)d_in[6];
  const float* nextE = (const float*)d_in[7];
  const float* pretE = (const float*)d_in[8];
  const float* t_rw = (const float*)d_in[9];
  const float* t_rb = (const float*)d_in[10];
  const float* termE = (const float*)d_in[11];
  float* out = (float*)d_out;

  char* ws = (char*)d_ws;
  size_t off = 0;
  auto alloc = [&](size_t bytes) {
    void* p = ws + off;
    off = (off + bytes + 255) & ~(size_t)255;
    return p;
  };
  float* w_start = (float*)alloc(CD * 4);
  float* w_fx = (float*)alloc(HD * 4);
  float* w_fx2 = (float*)alloc(HD * 4);
  unsigned short* w_tlg = (unsigned short*)alloc((size_t)CD * CD * 2);
  unsigned char* w_P8 = (unsigned char*)alloc((size_t)CD * CD);
  unsigned char* w_PT8 = (unsigned char*)alloc((size_t)CD * CD);
  float* w_fe = (float*)alloc((size_t)CD * HD * 4);
  unsigned short* w_logT = (unsigned short*)alloc((size_t)VD * CD * 2);
  float* w_part = (float*)alloc((size_t)125 * 1024 * 4);
  float* w_lse = (float*)alloc(CD * 4);
  unsigned short* w_em = (unsigned short*)alloc((size_t)8 * 256 * 512 * 16 * 2);
  float* w_aF = (float*)alloc((size_t)ND * CD * 4);
  float* w_aB = (float*)alloc((size_t)ND * CD * 4);
  if (off > ws_size) return;

  hipFuncSetAttribute(reinterpret_cast<const void*>(k_gemm),
                      hipFuncAttributeMaxDynamicSharedMemorySize, GEMM_LDS);

  k_fx<<<1, 256, 0, stream>>>(s_emb, s_w, s_b, w_fx);
  k_mlp<<<1, 256, 0, stream>>>(w_fx, s_rw, s_rb, w_fx2);
  k_slog<<<1, 256, 0, stream>>>(w_fx2, nextE, w_start);

  k_gemm<<<dim3(4, 4), 512, GEMM_LDS, stream>>>(stateE, nextE, w_tlg, CD);
  k_smrow<<<CD, 256, 0, stream>>>(w_tlg, w_P8);
  k_tr8<<<dim3(4, 4), 256, 0, stream>>>(w_P8, w_PT8);

  k_mlp<<<CD, 256, 0, stream>>>(pretE, t_rw, t_rb, w_fe);
  k_gemm<<<dim3(250, 4), 512, GEMM_LDS, stream>>>(termE, w_fe, w_logT, CD);

  k_lsep<<<125, 512, 0, stream>>>(w_logT, w_part);
  k_lsef<<<1, 512, 0, stream>>>(w_part, w_lse);

  k_gather<<<2048, 512, 0, stream>>>(text, w_logT, w_lse, w_em);

  k_scan<<<8, 512, 0, stream>>>(w_P8, w_PT8, w_em, w_start, w_aF, w_aB);
  k_meet<<<1, 512, 0, stream>>>(w_aF, w_aB, out);
}

// Round 4
// 738.154 us; speedup vs baseline: 1.7977x; 1.1489x over previous
//
#include <hip/hip_runtime.h>
#include <hip/hip_bf16.h>

#define HD 256
#define CD 512
#define VD 32000
#define ND 64
#define TD 512

typedef __attribute__((ext_vector_type(8))) short short8;
typedef __attribute__((ext_vector_type(4))) float floatx4;
typedef __attribute__((ext_vector_type(8))) int int32x8;

__device__ inline float bf2f(unsigned short u) {
  union { unsigned u; float f; } t; t.u = ((unsigned)u) << 16; return t.f;
}
__device__ inline unsigned short f2bf(float x) {
  union { float f; unsigned u; } t; t.f = x;
  unsigned u = t.u;
  u += 0x7FFFu + ((u >> 16) & 1u);
  return (unsigned short)(u >> 16);
}
__device__ inline float bf_lo(unsigned u) { union { unsigned u; float f; } t; t.u = u << 16; return t.f; }
__device__ inline float bf_hi(unsigned u) { union { unsigned u; float f; } t; t.u = u & 0xFFFF0000u; return t.f; }

__device__ inline floatx4 zf4() { floatx4 v; v[0] = v[1] = v[2] = v[3] = 0.f; return v; }
__device__ inline floatx4 mfma16(short8 a, short8 b, floatx4 c) {
  return __builtin_amdgcn_mfma_f32_16x16x32_bf16(a, b, c, 0, 0, 0);
}
// MX-scaled fp8 MFMA, scales pinned to 1.0 (E8M0 bias 127 = 0x7F)
__device__ inline floatx4 mfma_mx(int32x8 a, int32x8 b, floatx4 c) {
  return __builtin_amdgcn_mfma_scale_f32_16x16x128_f8f6f4(
      a, b, c, 0, 0, 0, 0x7F7F7F7F, 0, 0x7F7F7F7F);
}

// ---------------- small start-vector kernels ----------------

__global__ void k_fx(const float* __restrict__ emb, const float* __restrict__ W,
                     const float* __restrict__ b, float* __restrict__ out) {
  __shared__ float e[HD];
  int j = threadIdx.x;
  e[j] = emb[j];
  __syncthreads();
  float a = b[j];
#pragma unroll 4
  for (int i = 0; i < HD; ++i) a += e[i] * W[i * HD + j];
  out[j] = a;
}

// x (rows x 256) -> two ResLayers -> out  (one block per row, 256 threads)
__global__ void k_mlp(const float* __restrict__ inp, const float* __restrict__ rw,
                      const float* __restrict__ rb, float* __restrict__ out) {
  __shared__ float x[HD], h[HD];
  int j = threadIdx.x;
  int row = blockIdx.x;
  x[j] = inp[row * HD + j];
  __syncthreads();
  for (int L = 0; L < 2; ++L) {
    const float* w1 = rw + (size_t)(L * 2 + 0) * HD * HD;
    const float* b1 = rb + (L * 2 + 0) * HD;
    const float* w2 = rw + (size_t)(L * 2 + 1) * HD * HD;
    const float* b2 = rb + (L * 2 + 1) * HD;
    float a = b1[j];
#pragma unroll 4
    for (int i = 0; i < HD; ++i) a += x[i] * w1[i * HD + j];
    a = fmaxf(a, 0.f);
    h[j] = a;
    __syncthreads();
    float o = b2[j];
#pragma unroll 4
    for (int i = 0; i < HD; ++i) o += h[i] * w2[i * HD + j];
    x[j] = x[j] + fmaxf(o, 0.f);
    __syncthreads();
  }
  out[row * HD + j] = x[j];
}

// start logits + log_softmax (1 block, 256 threads)
__global__ void k_slog(const float* __restrict__ fx, const float* __restrict__ nextE,
                       float* __restrict__ startO) {
  __shared__ float x[HD];
  __shared__ float red[4];
  int j = threadIdx.x;
  x[j] = fx[j];
  __syncthreads();
  float lg0 = 0.f, lg1 = 0.f;
#pragma unroll 4
  for (int hh = 0; hh < HD; ++hh) {
    float xv = x[hh];
    lg0 += xv * nextE[j * HD + hh];
    lg1 += xv * nextE[(j + 256) * HD + hh];
  }
  float m = fmaxf(lg0, lg1);
#pragma unroll
  for (int sh = 1; sh <= 32; sh <<= 1) m = fmaxf(m, __shfl_xor(m, sh));
  if ((j & 63) == 0) red[j >> 6] = m;
  __syncthreads();
  m = fmaxf(fmaxf(red[0], red[1]), fmaxf(red[2], red[3]));
  __syncthreads();
  float s = __expf(lg0 - m) + __expf(lg1 - m);
#pragma unroll
  for (int sh = 1; sh <= 32; sh <<= 1) s += __shfl_xor(s, sh);
  if ((j & 63) == 0) red[j >> 6] = s;
  __syncthreads();
  s = red[0] + red[1] + red[2] + red[3];
  float ls = __logf(s);
  startO[j] = lg0 - m - ls;
  startO[j + 256] = lg1 - m - ls;
}

// ---------------- generic NT GEMM (M x 256) x (N x 256)^T -> bf16 out[M][N] ----------------
#define GEMM_LDS (2 * 128 * 528)
__global__ __launch_bounds__(512) void k_gemm(const float* __restrict__ A,
                                              const float* __restrict__ B,
                                              unsigned short* __restrict__ out,
                                              int ldo) {
  extern __shared__ char smem[];
  char* sA = smem;             // [128][528 bytes] bf16, K contiguous
  char* sB = smem + 128 * 528;
  const int tid = threadIdx.x;
  const int mbase = blockIdx.x * 128, nbase = blockIdx.y * 128;
  {
    int row = tid >> 2, seg = tid & 3;
    const float4* srcA = (const float4*)(A + (size_t)(mbase + row) * HD + seg * 64);
    const float4* srcB = (const float4*)(B + (size_t)(nbase + row) * HD + seg * 64);
    uint2* dA = (uint2*)(sA + row * 528 + seg * 128);
    uint2* dB = (uint2*)(sB + row * 528 + seg * 128);
#pragma unroll
    for (int i = 0; i < 16; ++i) {
      float4 va = srcA[i];
      float4 vb = srcB[i];
      dA[i] = make_uint2((unsigned)f2bf(va.x) | ((unsigned)f2bf(va.y) << 16),
                         (unsigned)f2bf(va.z) | ((unsigned)f2bf(va.w) << 16));
      dB[i] = make_uint2((unsigned)f2bf(vb.x) | ((unsigned)f2bf(vb.y) << 16),
                         (unsigned)f2bf(vb.z) | ((unsigned)f2bf(vb.w) << 16));
    }
  }
  __syncthreads();
  const int w = tid >> 6, l = tid & 63, l15 = l & 15, quad = l >> 4;
  floatx4 acc[8];
#pragma unroll
  for (int nt = 0; nt < 8; ++nt) acc[nt] = zf4();
  const char* arow = sA + (w * 16 + l15) * 528 + quad * 16;
  const char* brow = sB + l15 * 528 + quad * 16;
#pragma unroll
  for (int kc = 0; kc < 8; ++kc) {
    short8 a = *(const short8*)(arow + kc * 64);
#pragma unroll
    for (int nt = 0; nt < 8; ++nt) {
      short8 b = *(const short8*)(brow + nt * 16 * 528 + kc * 64);
      acc[nt] = mfma16(a, b, acc[nt]);
    }
  }
#pragma unroll
  for (int nt = 0; nt < 8; ++nt)
#pragma unroll
    for (int r = 0; r < 4; ++r) {
      int m = mbase + w * 16 + quad * 4 + r;
      int n = nbase + nt * 16 + l15;
      out[(size_t)m * ldo + n] = f2bf(acc[nt][r]);
    }
}

// ---------------- transition row-softmax -> P fp8 (x64 scale) ----------------
__global__ void k_smrow(const unsigned short* __restrict__ lg, unsigned char* __restrict__ P8) {
  __shared__ float red[4];
  int row = blockIdx.x, j = threadIdx.x;
  float v0 = bf2f(lg[row * CD + j]);
  float v1 = bf2f(lg[row * CD + 256 + j]);
  float m = fmaxf(v0, v1);
#pragma unroll
  for (int sh = 1; sh <= 32; sh <<= 1) m = fmaxf(m, __shfl_xor(m, sh));
  if ((j & 63) == 0) red[j >> 6] = m;
  __syncthreads();
  m = fmaxf(fmaxf(red[0], red[1]), fmaxf(red[2], red[3]));
  __syncthreads();
  float e0 = __expf(v0 - m), e1 = __expf(v1 - m);
  float s = e0 + e1;
#pragma unroll
  for (int sh = 1; sh <= 32; sh <<= 1) s += __shfl_xor(s, sh);
  if ((j & 63) == 0) red[j >> 6] = s;
  __syncthreads();
  s = red[0] + red[1] + red[2] + red[3];
  float inv = 64.0f / s;   // gamma_P = 64 folded in
  int b0 = __builtin_amdgcn_cvt_pk_fp8_f32(e0 * inv, e0 * inv, 0, false);
  int b1 = __builtin_amdgcn_cvt_pk_fp8_f32(e1 * inv, e1 * inv, 0, false);
  P8[row * CD + j] = (unsigned char)(b0 & 0xff);
  P8[row * CD + 256 + j] = (unsigned char)(b1 & 0xff);
}

// transpose fp8 512x512: P8 -> PT8
__global__ __launch_bounds__(256) void k_tr8(const unsigned char* __restrict__ P,
                                             unsigned char* __restrict__ PT) {
  __shared__ unsigned char t[128][144];
  int rb = blockIdx.x * 128, cb = blockIdx.y * 128;
  int tid = threadIdx.x;
  {
    int r = tid >> 1, h = tid & 1;
    const uint4* src = (const uint4*)(P + (size_t)(rb + r) * CD + cb + h * 64);
    uint4* dst = (uint4*)(&t[r][h * 64]);
#pragma unroll
    for (int i = 0; i < 4; ++i) dst[i] = src[i];
  }
  __syncthreads();
  {
    int c = tid >> 1, h = tid & 1;
    unsigned char buf[64];
#pragma unroll
    for (int i = 0; i < 64; ++i) buf[i] = t[h * 64 + i][c];
    uint4* dst = (uint4*)(PT + (size_t)(cb + c) * CD + rb + h * 64);
    const uint4* s = (const uint4*)buf;
#pragma unroll
    for (int i = 0; i < 4; ++i) dst[i] = s[i];
  }
}

// ---------------- vocab log-sum-exp over columns of logT [V][C] ----------------
__global__ __launch_bounds__(512) void k_lsep(const unsigned short* __restrict__ logT,
                                              float* __restrict__ part) {
  int c = threadIdx.x, b = blockIdx.x;
  const unsigned short* p = logT + (size_t)b * 256 * CD + c;
  float m = -1e30f, s = 0.f;
  for (int i = 0; i < 256; ++i) {
    float v = bf2f(p[(size_t)i * CD]);
    float nm = fmaxf(m, v);
    s = s * __expf(m - nm) + __expf(v - nm);
    m = nm;
  }
  part[b * 1024 + c] = m;
  part[b * 1024 + 512 + c] = s;
}

__global__ void k_lsef(const float* __restrict__ part, float* __restrict__ lse) {
  int c = threadIdx.x;
  float m = -1e30f, s = 0.f;
  for (int i = 0; i < 125; ++i) {
    float mi = part[i * 1024 + c], si = part[i * 1024 + 512 + c];
    float nm = fmaxf(m, mi);
    s = s * __expf(m - nm) + si * __expf(mi - nm);
    m = nm;
  }
  lse[c] = m + __logf(s);
}

// ---------------- gather E = exp(emission log-prob) ----------------
// 8 old-style groups of 16 seqs; lane holds n = q*16 + l15,
// value j = nt*4+r at c = w*64 + nt*16 + quad*4 + r
__global__ __launch_bounds__(512) void k_gather(const int* __restrict__ text,
                                                const unsigned short* __restrict__ logT,
                                                const float* __restrict__ lse,
                                                unsigned short* __restrict__ em) {
  const int b = blockIdx.x;
  const int g = b >> 8, t = b & 255;
  const int dir = g >> 2, q = g & 3;
  const int tg = dir ? (511 - t) : t;
  const int tid = threadIdx.x, w = tid >> 6, l = tid & 63;
  const int l15 = l & 15, quad = l >> 4;
  const int n = q * 16 + l15;
  const int tok = text[n * TD + tg];
  const unsigned short* row = logT + (size_t)tok * CD;
  unsigned outp[8];
#pragma unroll
  for (int nt = 0; nt < 4; ++nt) {
    int c0 = w * 64 + nt * 16 + quad * 4;
    uint2 rv = *(const uint2*)(row + c0);
    float4 ls = *(const float4*)(lse + c0);
    float E0 = __expf(bf_lo(rv.x) - ls.x);
    float E1 = __expf(bf_hi(rv.x) - ls.y);
    float E2 = __expf(bf_lo(rv.y) - ls.z);
    float E3 = __expf(bf_hi(rv.y) - ls.w);
    outp[nt * 2 + 0] = (unsigned)f2bf(E0) | ((unsigned)f2bf(E1) << 16);
    outp[nt * 2 + 1] = (unsigned)f2bf(E2) | ((unsigned)f2bf(E3) << 16);
  }
  uint4* dst = (uint4*)(em + (((size_t)b * 8 + w) * 64 + l) * 16);
  dst[0] = make_uint4(outp[0], outp[1], outp[2], outp[3]);
  dst[1] = make_uint4(outp[4], outp[5], outp[6], outp[7]);
}

// ---------------- the scan: 16 blocks (8 fwd + 8 bwd), 8 seqs each ----------------
// B-operand columns duplicated 2x (col l15 <-> seq l15&7) so each block has
// 1 wave/SIMD of MFMA issue. P resident in registers (fp8 A-operand for
// mfma_scale 16x16x128); alpha staged in conflict-free LDS (8 rows x 528B).
__global__ __launch_bounds__(512, 2) void k_scan(const unsigned char* __restrict__ P8,
                                                 const unsigned char* __restrict__ PT8,
                                                 const unsigned short* __restrict__ em,
                                                 const float* __restrict__ startv,
                                                 float* __restrict__ alphaF,
                                                 float* __restrict__ alphaB) {
  __shared__ unsigned char Abuf[8 * 528];    // [seq&7][k fp8], stride 528 (bank-staggered)
  __shared__ float scratch[16 * 8];          // [l15][wave]
  const int g = blockIdx.x, dir = g >> 3, q = g & 7;
  const int tid = threadIdx.x, w = tid >> 6, l = tid & 63;
  const int l15 = l & 15, quad = l >> 4;
  const int r7 = l15 & 7;
  const int colbase = w * 64;
  const unsigned char* Pb = dir ? P8 : PT8;  // [out state][src state], x64-scaled fp8

  // A-operand fragments: A[m = out-state local l15][k = kc*128 + quad*32 + j]
  int32x8 Prf[4][4];
#pragma unroll
  for (int kc = 0; kc < 4; ++kc)
#pragma unroll
    for (int mt = 0; mt < 4; ++mt) {
      const uint4* p = (const uint4*)(Pb + (size_t)(colbase + mt * 16 + l15) * CD + kc * 128 + quad * 32);
      uint4 x0 = p[0], x1 = p[1];
      Prf[kc][mt] = (int32x8){(int)x0.x, (int)x0.y, (int)x0.z, (int)x0.w,
                              (int)x1.x, (int)x1.y, (int)x1.z, (int)x1.w};
    }

  // conflict-free LDS addresses (8 rows, 528B stride -> each row own bank group)
  unsigned char* wrbase = Abuf + r7 * 528 + colbase + quad * 4;
  const unsigned char* rdrow = Abuf + r7 * 528;

  // em lane remap into the 8-group gather layout
  const int go = dir * 4 + (q >> 1);
  const int o = quad * 16 + (q & 1) * 8 + r7;
  const unsigned short* emp = em + (((size_t)go * 256 * 8 + w) * 64 + o) * 16;
  const size_t emstride = 8 * 64 * 16;

  float Msum = 0.f;
  const float LGAP = 6.93147181f;  // log(16*64)
  const float LGA = 2.77258872f;   // log 16
  const float LGP = 4.15888308f;   // log 64

  auto tail = [&](float* v, float sub) {
    float m = fmaxf(fmaxf(fmaxf(v[0], v[1]), fmaxf(v[2], v[3])),
                    fmaxf(fmaxf(v[4], v[5]), fmaxf(v[6], v[7])));
    float m2 = fmaxf(fmaxf(fmaxf(v[8], v[9]), fmaxf(v[10], v[11])),
                     fmaxf(fmaxf(v[12], v[13]), fmaxf(v[14], v[15])));
    m = fmaxf(m, m2);
    m = fmaxf(m, __shfl_xor(m, 16));
    m = fmaxf(m, __shfl_xor(m, 32));
    if (quad == 0) scratch[l15 * 8 + w] = m;
    __syncthreads();
    const floatx4* sr = (const floatx4*)(scratch + l15 * 8);
    floatx4 s0 = sr[0], s1 = sr[1];
    m = fmaxf(fmaxf(fmaxf(s0[0], s0[1]), fmaxf(s0[2], s0[3])),
              fmaxf(fmaxf(s1[0], s1[1]), fmaxf(s1[2], s1[3])));
    float inv = __builtin_amdgcn_rcpf(m) * 16.0f;  // gamma_A = 16
    Msum += __logf(m) - sub;
    if (l15 < 8) {
#pragma unroll
      for (int mt = 0; mt < 4; ++mt) {
        int pk = __builtin_amdgcn_cvt_pk_fp8_f32(v[mt * 4 + 0] * inv, v[mt * 4 + 1] * inv, 0, false);
        pk = __builtin_amdgcn_cvt_pk_fp8_f32(v[mt * 4 + 2] * inv, v[mt * 4 + 3] * inv, pk, true);
        *(int*)(wrbase + mt * 16) = pk;
      }
    }
    __syncthreads();
  };

  // ---- init: A0 = exp(start) * E0 (fwd) or E0 (bwd)
  {
    const uint4* ep = (const uint4*)emp;
    uint4 e0 = ep[0], e1 = ep[1];
    unsigned eu[8] = {e0.x, e0.y, e0.z, e0.w, e1.x, e1.y, e1.z, e1.w};
    float v[16];
#pragma unroll
    for (int mt = 0; mt < 4; ++mt)
#pragma unroll
      for (int r = 0; r < 4; ++r) {
        int j = mt * 4 + r;
        float E = (j & 1) ? bf_hi(eu[j >> 1]) : bf_lo(eu[j >> 1]);
        float st = dir ? 1.f : __expf(startv[colbase + mt * 16 + quad * 4 + r]);
        v[j] = st * E;
      }
    tail(v, LGA);
  }

  // current-step em (for s=1)
  uint4 ec0, ec1;
  {
    const uint4* ep = (const uint4*)(emp + emstride);
    ec0 = ep[0]; ec1 = ep[1];
  }
  // uniform steps: fwd s=1..254, bwd s=1..255 (final peeled)
  const int nloop = dir ? 255 : 254;
  for (int s = 1; s <= nloop; ++s) {
    int32x8 bfr[4];
#pragma unroll
    for (int kc = 0; kc < 4; ++kc) {
      int u0 = (kc * 8 + quad * 2) * 16;
      uint4 x0 = *(const uint4*)(rdrow + u0);
      uint4 x1 = *(const uint4*)(rdrow + u0 + 16);
      bfr[kc] = (int32x8){(int)x0.x, (int)x0.y, (int)x0.z, (int)x0.w,
                          (int)x1.x, (int)x1.y, (int)x1.z, (int)x1.w};
    }
    // prefetch next step's em while MFMAs run (s+1 <= 256; tail spill lands in aF ws, unused)
    const uint4* ep = (const uint4*)(emp + (size_t)(s + 1) * emstride);
    uint4 en0 = ep[0], en1 = ep[1];
    floatx4 acc[4];
#pragma unroll
    for (int mt = 0; mt < 4; ++mt) acc[mt] = zf4();
#pragma unroll
    for (int kc = 0; kc < 4; ++kc) {
      acc[0] = mfma_mx(Prf[kc][0], bfr[kc], acc[0]);
      acc[1] = mfma_mx(Prf[kc][1], bfr[kc], acc[1]);
      acc[2] = mfma_mx(Prf[kc][2], bfr[kc], acc[2]);
      acc[3] = mfma_mx(Prf[kc][3], bfr[kc], acc[3]);
    }
    unsigned eu[8] = {ec0.x, ec0.y, ec0.z, ec0.w, ec1.x, ec1.y, ec1.z, ec1.w};
    float v[16];
#pragma unroll
    for (int mt = 0; mt < 4; ++mt)
#pragma unroll
      for (int r = 0; r < 4; ++r) {
        int j = mt * 4 + r;
        float E = (j & 1) ? bf_hi(eu[j >> 1]) : bf_lo(eu[j >> 1]);
        v[j] = acc[mt][r] * E;
      }
    tail(v, LGAP);
    ec0 = en0; ec1 = en1;
  }
  // ---- final step (fwd: s=255 with em; bwd: s=256 with E=1) + store
  {
    int32x8 bfr[4];
#pragma unroll
    for (int kc = 0; kc < 4; ++kc) {
      int u0 = (kc * 8 + quad * 2) * 16;
      uint4 x0 = *(const uint4*)(rdrow + u0);
      uint4 x1 = *(const uint4*)(rdrow + u0 + 16);
      bfr[kc] = (int32x8){(int)x0.x, (int)x0.y, (int)x0.z, (int)x0.w,
                          (int)x1.x, (int)x1.y, (int)x1.z, (int)x1.w};
    }
    floatx4 acc[4];
#pragma unroll
    for (int mt = 0; mt < 4; ++mt) acc[mt] = zf4();
#pragma unroll
    for (int kc = 0; kc < 4; ++kc) {
      acc[0] = mfma_mx(Prf[kc][0], bfr[kc], acc[0]);
      acc[1] = mfma_mx(Prf[kc][1], bfr[kc], acc[1]);
      acc[2] = mfma_mx(Prf[kc][2], bfr[kc], acc[2]);
      acc[3] = mfma_mx(Prf[kc][3], bfr[kc], acc[3]);
    }
    unsigned eu[8] = {ec0.x, ec0.y, ec0.z, ec0.w, ec1.x, ec1.y, ec1.z, ec1.w};
    if (l15 < 8) {
      float* dst = dir ? alphaB : alphaF;
#pragma unroll
      for (int mt = 0; mt < 4; ++mt) {
        float4 ov;
        float vv[4];
#pragma unroll
        for (int r = 0; r < 4; ++r) {
          int j = mt * 4 + r;
          float E = dir ? 1.f : ((j & 1) ? bf_hi(eu[j >> 1]) : bf_lo(eu[j >> 1]));
          vv[r] = acc[mt][r] * E;
        }
        ov.x = __logf(vv[0]) + Msum - LGP;
        ov.y = __logf(vv[1]) + Msum - LGP;
        ov.z = __logf(vv[2]) + Msum - LGP;
        ov.w = __logf(vv[3]) + Msum - LGP;
        *(float4*)&dst[(size_t)(q * 8 + l15) * CD + colbase + mt * 16 + quad * 4] = ov;
      }
    }
  }
}

// ---------------- meet in the middle: evidence = sum_n lse_c(aF + aB) ----------------
__global__ void k_meet(const float* __restrict__ aF, const float* __restrict__ aB,
                       float* __restrict__ out) {
  __shared__ float wsum[8];
  int tid = threadIdx.x, w = tid >> 6, l = tid & 63;
  float ev = 0.f;
  for (int i = 0; i < 8; ++i) {
    int n = w * 8 + i;
    float x[8];
    float m = -1e30f;
#pragma unroll
    for (int k = 0; k < 8; ++k) {
      x[k] = aF[n * CD + k * 64 + l] + aB[n * CD + k * 64 + l];
      m = fmaxf(m, x[k]);
    }
#pragma unroll
    for (int sh = 1; sh <= 32; sh <<= 1) m = fmaxf(m, __shfl_xor(m, sh));
    float s = 0.f;
#pragma unroll
    for (int k = 0; k < 8; ++k) s += __expf(x[k] - m);
#pragma unroll
    for (int sh = 1; sh <= 32; sh <<= 1) s += __shfl_xor(s, sh);
    ev += m + __logf(s);
  }
  if (l == 0) wsum[w] = ev;
  __syncthreads();
  if (tid == 0) {
    float tot = 0.f;
    for (int i = 0; i < 8; ++i) tot += wsum[i];
    out[0] = tot;
  }
}

// ---------------- host ----------------
extern "C" void kernel_launch(void* const* d_in, const int* in_sizes, int n_in,
                              void* d_out, int out_size, void* d_ws, size_t ws_size,
                              hipStream_t stream) {
  (void)in_sizes; (void)n_in; (void)out_size;
  const int* text = (const int*)d_in[0];
  const float* s_emb = (const float*)d_in[1];
  const float* s_w = (const float*)d_in[2];
  const float* s_b = (const float*)d_in[3];
  const float* s_rw = (const float*)d_in[4];
  const float* s_rb = (const float*)d_in[5];
  const float* stateE = (const float*)d_in[6];
  const float* nextE = (const float*)d_in[7];
  const float* pretE = (const float*)d_in[8];
  const float* t_rw = (const float*)d_in[9];
  const float* t_rb = (const float*)d_in[10];
  const float* termE = (const float*)d_in[11];
  float* out = (float*)d_out;

  char* ws = (char*)d_ws;
  size_t off = 0;
  auto alloc = [&](size_t bytes) {
    void* p = ws + off;
    off = (off + bytes + 255) & ~(size_t)255;
    return p;
  };
  float* w_start = (float*)alloc(CD * 4);
  float* w_fx = (float*)alloc(HD * 4);
  float* w_fx2 = (float*)alloc(HD * 4);
  unsigned short* w_tlg = (unsigned short*)alloc((size_t)CD * CD * 2);
  unsigned char* w_P8 = (unsigned char*)alloc((size_t)CD * CD);
  unsigned char* w_PT8 = (unsigned char*)alloc((size_t)CD * CD);
  float* w_fe = (float*)alloc((size_t)CD * HD * 4);
  unsigned short* w_logT = (unsigned short*)alloc((size_t)VD * CD * 2);
  float* w_part = (float*)alloc((size_t)125 * 1024 * 4);
  float* w_lse = (float*)alloc(CD * 4);
  unsigned short* w_em = (unsigned short*)alloc((size_t)8 * 256 * 512 * 16 * 2);
  float* w_aF = (float*)alloc((size_t)ND * CD * 4);
  float* w_aB = (float*)alloc((size_t)ND * CD * 4);
  if (off > ws_size) return;

  hipFuncSetAttribute(reinterpret_cast<const void*>(k_gemm),
                      hipFuncAttributeMaxDynamicSharedMemorySize, GEMM_LDS);

  k_fx<<<1, 256, 0, stream>>>(s_emb, s_w, s_b, w_fx);
  k_mlp<<<1, 256, 0, stream>>>(w_fx, s_rw, s_rb, w_fx2);
  k_slog<<<1, 256, 0, stream>>>(w_fx2, nextE, w_start);

  k_gemm<<<dim3(4, 4), 512, GEMM_LDS, stream>>>(stateE, nextE, w_tlg, CD);
  k_smrow<<<CD, 256, 0, stream>>>(w_tlg, w_P8);
  k_tr8<<<dim3(4, 4), 256, 0, stream>>>(w_P8, w_PT8);

  k_mlp<<<CD, 256, 0, stream>>>(pretE, t_rw, t_rb, w_fe);
  k_gemm<<<dim3(250, 4), 512, GEMM_LDS, stream>>>(termE, w_fe, w_logT, CD);

  k_lsep<<<125, 512, 0, stream>>>(w_logT, w_part);
  k_lsef<<<1, 512, 0, stream>>>(w_part, w_lse);

  k_gather<<<2048, 512, 0, stream>>>(text, w_logT, w_lse, w_em);

  k_scan<<<16, 512, 0, stream>>>(w_P8, w_PT8, w_em, w_start, w_aF, w_aB);
  k_meet<<<1, 512, 0, stream>>>(w_aF, w_aB, out);
}